// Round 18
// baseline (74.007 us; speedup 1.0000x reference)
//
#include <hip/hip_runtime.h>
#include <hip/hip_bf16.h>
#include <stdint.h>

// Problem constants
#define B_    2
#define S_    2048
#define H_    16
#define DH_   64
#define D_    1024
#define ND3   3072      // 3*D
#define MTOT  4096      // B*S
#define L2E   1.4426950408889634f
#define MASKVAL (-3.0e38f)   // causal mask: exp2(MASKVAL) == 0
#define SBIAS   (-14.0f)     // static softmax offset (log2 units)

typedef __attribute__((ext_vector_type(8))) short bf16x8;
typedef __attribute__((ext_vector_type(4))) short bf16x4;
typedef __attribute__((ext_vector_type(4))) float f32x4;

#if __has_builtin(__builtin_amdgcn_exp2f)
#define EXP2(x) __builtin_amdgcn_exp2f(x)
#else
#define EXP2(x) exp2f(x)
#endif

__device__ inline short f2bs(float f) {
  __hip_bfloat16 h = __float2bfloat16(f);
  return *reinterpret_cast<short*>(&h);
}

__device__ inline void gl_lds16(const void* g, void* l) {
  __builtin_amdgcn_global_load_lds(
      (const __attribute__((address_space(1))) uint32_t*)g,
      (__attribute__((address_space(3))) uint32_t*)l, 16, 0, 0);
}

// --------------------------------------- fused prep: x->bf16 and W->Wt bf16
__global__ __launch_bounds__(256) void prep_kernel(
    const float* __restrict__ X, const float* __restrict__ Wq,
    const float* __restrict__ Wk, const float* __restrict__ Wv,
    short* __restrict__ Xb, short* __restrict__ Wt) {
  __shared__ float t[32][33];
  int bid = blockIdx.x;
  if (bid < 4096) {
    const int i = (bid * 256 + threadIdx.x) * 4;
    float4 v = *reinterpret_cast<const float4*>(X + i);
    bf16x4 o;
    o[0] = f2bs(v.x); o[1] = f2bs(v.y); o[2] = f2bs(v.z); o[3] = f2bs(v.w);
    *reinterpret_cast<bf16x4*>(Xb + i) = o;
  } else {
    bid -= 4096;
    const int z = bid >> 10;             // 0..2 : Wq/Wk/Wv
    const int rem = bid & 1023;
    const int n0 = (rem & 31) * 32, k0 = (rem >> 5) * 32;
    const int x = threadIdx.x & 31, y = threadIdx.x >> 5;   // y in 0..7
    const float* W = z == 0 ? Wq : (z == 1 ? Wk : Wv);
    short* out = Wt + (size_t)z * (D_ * D_);
#pragma unroll
    for (int i = 0; i < 4; ++i)
      t[y + 8 * i][x] = W[(size_t)(k0 + y + 8 * i) * D_ + n0 + x];
    __syncthreads();
#pragma unroll
    for (int i = 0; i < 4; ++i)
      out[(size_t)(n0 + y + 8 * i) * D_ + k0 + x] = f2bs(t[x][y + 8 * i]);
  }
}

// ------------------------------------------------- QKV GEMM, 256x192 8-phase
// (r17 structure; V epilogue reverted to PLAIN transposed Vt[bh][dh][s] —
// the kv-split attention reads V as b64 fragments, no pair permutation.)
__global__ __launch_bounds__(512, 2) void qkv_gemm_kernel(
    const short* __restrict__ Xb, const short* __restrict__ Wt,
    const float* __restrict__ bq, const float* __restrict__ bk,
    const float* __restrict__ bv, short* __restrict__ QKV,
    short* __restrict__ Vt) {
  __shared__ char Lds[114688];   // buf d: A @ d*57344 (32KB), B @ +32768 (24KB)
  const int tid = threadIdx.x;
  const int lane = tid & 63;
  const int wid = tid >> 6;
  const int l15 = lane & 15, lg = lane >> 4;
  const int wm = wid >> 2, wn = wid & 3;
  const int bid = blockIdx.x;
  const int wgid = (bid & 7) * 32 + (bid >> 3);
  const int m0 = (wgid >> 4) * 256, n0 = (wgid & 15) * 192;

  const int srow = tid >> 3;                         // 0..63
  const int scol = ((tid & 7) ^ (srow & 7)) * 8;
  const short* pa = Xb + (size_t)(m0 + srow) * D_ + scol;
  const short* pb = Wt + (size_t)(n0 + srow) * D_ + scol;
  char* sdst = Lds + (tid & 448) * 16;               // wave-uniform base

  const int abase = wm * 16384;                      // A rows wm*128..+127
  int a_off[8][2], b_off[3][2];
#pragma unroll
  for (int mr = 0; mr < 8; ++mr)
#pragma unroll
    for (int ks = 0; ks < 2; ++ks)
      a_off[mr][ks] =
          (mr * 16 + l15) * 128 + ((((ks * 4 + lg)) ^ (l15 & 7)) << 4);
#pragma unroll
  for (int nr = 0; nr < 3; ++nr)
#pragma unroll
    for (int ks = 0; ks < 2; ++ks)
      b_off[nr][ks] = (wn * 48 + nr * 16 + l15) * 128 +
                      ((((ks * 4 + lg)) ^ (l15 & 7)) << 4);

  f32x4 acc[8][3];
#pragma unroll
  for (int i = 0; i < 8; ++i)
#pragma unroll
    for (int j = 0; j < 3; ++j) acc[i][j] = (f32x4){0.f, 0.f, 0.f, 0.f};

#define BARRIER()                                                             \
  __builtin_amdgcn_s_barrier();                                               \
  __builtin_amdgcn_sched_barrier(0)

  gl_lds16(pa, sdst);
  gl_lds16(pa + (size_t)64 * D_, sdst + 8192);
  gl_lds16(pa + (size_t)128 * D_, sdst + 16384);
  gl_lds16(pa + (size_t)192 * D_, sdst + 24576);
  gl_lds16(pb, sdst + 32768);
  gl_lds16(pb + (size_t)64 * D_, sdst + 40960);
  gl_lds16(pb + (size_t)128 * D_, sdst + 49152);
  asm volatile("s_waitcnt vmcnt(0)" ::: "memory");
  BARRIER();

#define TILE(J, DL)                                                           \
  {                                                                           \
    const int j_ = (J);                                                       \
    const bool stg = (j_ + 1 < 16);                                           \
    const int RD = (DL) * 57344;                                              \
    const int WD = (1 - (DL)) * 57344;                                        \
    const short* pa1 = pa + (j_ + 1) * 64;                                    \
    const short* pb1 = pb + (j_ + 1) * 64;                                    \
    bf16x8 af[4], bf0, bf1, bf2;                                              \
    /* P0: stage A-lo + B0,B1; frags B ks0 + A ks0 mr0-3; MFMA acc[0..3] */   \
    if (stg) {                                                                \
      gl_lds16(pa1, sdst + WD);                                               \
      gl_lds16(pa1 + (size_t)64 * D_, sdst + WD + 8192);                      \
      gl_lds16(pb1, sdst + WD + 32768);                                       \
      gl_lds16(pb1 + (size_t)64 * D_, sdst + WD + 40960);                     \
    }                                                                         \
    bf0 = *reinterpret_cast<const bf16x8*>(Lds + RD + 32768 + b_off[0][0]);   \
    bf1 = *reinterpret_cast<const bf16x8*>(Lds + RD + 32768 + b_off[1][0]);   \
    bf2 = *reinterpret_cast<const bf16x8*>(Lds + RD + 32768 + b_off[2][0]);   \
    _Pragma("unroll") for (int mr = 0; mr < 4; ++mr) af[mr] =                 \
        *reinterpret_cast<const bf16x8*>(Lds + RD + abase + a_off[mr][0]);    \
    BARRIER();                                                                \
    __builtin_amdgcn_s_setprio(1);                                            \
    _Pragma("unroll") for (int mr = 0; mr < 4; ++mr) {                        \
      acc[mr][0] = __builtin_amdgcn_mfma_f32_16x16x32_bf16(af[mr], bf0,       \
                                                           acc[mr][0], 0, 0,  \
                                                           0);                \
      acc[mr][1] = __builtin_amdgcn_mfma_f32_16x16x32_bf16(af[mr], bf1,       \
                                                           acc[mr][1], 0, 0,  \
                                                           0);                \
      acc[mr][2] = __builtin_amdgcn_mfma_f32_16x16x32_bf16(af[mr], bf2,       \
                                                           acc[mr][2], 0, 0,  \
                                                           0);                \
    }                                                                         \
    __builtin_amdgcn_s_setprio(0);                                            \
    BARRIER();                                                                \
    /* P1: stage A-hi + B2; frags A ks0 mr4-7; MFMA acc[4..7] */              \
    if (stg) {                                                                \
      gl_lds16(pa1 + (size_t)128 * D_, sdst + WD + 16384);                    \
      gl_lds16(pa1 + (size_t)192 * D_, sdst + WD + 24576);                    \
      gl_lds16(pb1 + (size_t)128 * D_, sdst + WD + 49152);                    \
    }                                                                         \
    _Pragma("unroll") for (int mr = 0; mr < 4; ++mr) af[mr] =                 \
        *reinterpret_cast<const bf16x8*>(Lds + RD + abase +                   \
                                         a_off[mr + 4][0]);                   \
    BARRIER();                                                                \
    __builtin_amdgcn_s_setprio(1);                                            \
    _Pragma("unroll") for (int mr = 0; mr < 4; ++mr) {                        \
      acc[mr + 4][0] = __builtin_amdgcn_mfma_f32_16x16x32_bf16(               \
          af[mr], bf0, acc[mr + 4][0], 0, 0, 0);                              \
      acc[mr + 4][1] = __builtin_amdgcn_mfma_f32_16x16x32_bf16(               \
          af[mr], bf1, acc[mr + 4][1], 0, 0, 0);                              \
      acc[mr + 4][2] = __builtin_amdgcn_mfma_f32_16x16x32_bf16(               \
          af[mr], bf2, acc[mr + 4][2], 0, 0, 0);                              \
    }                                                                         \
    __builtin_amdgcn_s_setprio(0);                                            \
    BARRIER();                                                                \
    /* P2: frags B ks1 + A ks1 mr0-3; MFMA acc[0..3] */                       \
    bf0 = *reinterpret_cast<const bf16x8*>(Lds + RD + 32768 + b_off[0][1]);   \
    bf1 = *reinterpret_cast<const bf16x8*>(Lds + RD + 32768 + b_off[1][1]);   \
    bf2 = *reinterpret_cast<const bf16x8*>(Lds + RD + 32768 + b_off[2][1]);   \
    _Pragma("unroll") for (int mr = 0; mr < 4; ++mr) af[mr] =                 \
        *reinterpret_cast<const bf16x8*>(Lds + RD + abase + a_off[mr][1]);    \
    BARRIER();                                                                \
    __builtin_amdgcn_s_setprio(1);                                            \
    _Pragma("unroll") for (int mr = 0; mr < 4; ++mr) {                        \
      acc[mr][0] = __builtin_amdgcn_mfma_f32_16x16x32_bf16(af[mr], bf0,       \
                                                           acc[mr][0], 0, 0,  \
                                                           0);                \
      acc[mr][1] = __builtin_amdgcn_mfma_f32_16x16x32_bf16(af[mr], bf1,       \
                                                           acc[mr][1], 0, 0,  \
                                                           0);                \
      acc[mr][2] = __builtin_amdgcn_mfma_f32_16x16x32_bf16(af[mr], bf2,       \
                                                           acc[mr][2], 0, 0,  \
                                                           0);                \
    }                                                                         \
    __builtin_amdgcn_s_setprio(0);                                            \
    BARRIER();                                                                \
    /* P3: frags A ks1 mr4-7; MFMA acc[4..7]; drain staged loads */           \
    _Pragma("unroll") for (int mr = 0; mr < 4; ++mr) af[mr] =                 \
        *reinterpret_cast<const bf16x8*>(Lds + RD + abase +                   \
                                         a_off[mr + 4][1]);                   \
    BARRIER();                                                                \
    __builtin_amdgcn_s_setprio(1);                                            \
    _Pragma("unroll") for (int mr = 0; mr < 4; ++mr) {                        \
      acc[mr + 4][0] = __builtin_amdgcn_mfma_f32_16x16x32_bf16(               \
          af[mr], bf0, acc[mr + 4][0], 0, 0, 0);                              \
      acc[mr + 4][1] = __builtin_amdgcn_mfma_f32_16x16x32_bf16(               \
          af[mr], bf1, acc[mr + 4][1], 0, 0, 0);                              \
      acc[mr + 4][2] = __builtin_amdgcn_mfma_f32_16x16x32_bf16(               \
          af[mr], bf2, acc[mr + 4][2], 0, 0, 0);                              \
    }                                                                         \
    __builtin_amdgcn_s_setprio(0);                                            \
    asm volatile("s_waitcnt vmcnt(0)" ::: "memory");                          \
    BARRIER();                                                                \
  }

  for (int jj = 0; jj < 16; jj += 2) {
    TILE(jj, 0);
    TILE(jj + 1, 1);
  }
#undef TILE
#undef BARRIER

  const int wr = wm * 128;
#pragma unroll
  for (int nr = 0; nr < 3; ++nr) {
    const int col = n0 + wn * 48 + nr * 16 + l15;
    if (col < 2 * D_) {  // Q or K -> qkv rows
      float bias, qs;
      if (col < D_) { bias = bq[col];      qs = 0.125f * L2E; }
      else          { bias = bk[col - D_]; qs = 1.f; }
#pragma unroll
      for (int mr = 0; mr < 8; ++mr)
#pragma unroll
        for (int r = 0; r < 4; ++r) {
          const int row = m0 + wr + mr * 16 + lg * 4 + r;
          QKV[(size_t)row * ND3 + col] = f2bs((acc[mr][nr][r] + bias) * qs);
        }
    } else {  // V -> Vt[bh][dh][s] directly (plain fused transpose)
      const int f = col - 2 * D_;                    // v-feature 0..1023
      const float bias = bv[f];
      const int srow_base = (m0 & 2047) + wr + lg * 4;
      short* vout = Vt + ((size_t)((m0 >> 11) * H_ + (f >> 6)) * DH_ +
                          (f & 63)) * S_;
#pragma unroll
      for (int mr = 0; mr < 8; ++mr) {
        bf16x4 pv;
#pragma unroll
        for (int r = 0; r < 4; ++r) pv[r] = f2bs(acc[mr][nr][r] + bias);
        *reinterpret_cast<bf16x4*>(vout + srow_base + mr * 16) = pv;
      }
    }
  }
}

// ----------------------------------------------------------- flash attention
// r18: kv-SPLIT wave decomposition. Each wave owns kv slice [16*wid, +16) of
// every 64-kv tile, for ALL 64 q rows — so per wave-step the LDS reads are
// 2 b128 (K) + 4 b64 (V) instead of 16 b128: the 4x cross-wave K/V read
// redundancy of the q-split layout is eliminated (LDS pipe was ~60% of the
// step). No cross-wave softmax in the loop: no max (static SBIAS), and
// lsum/O are kv-partials reduced ONCE in an LDS epilogue (uniform exp2
// scale). Mask applies per-wave at t==qt. Stage-1-ahead, 2K+2V slots.
__global__ __launch_bounds__(256, 3) void attn_kernel(
    const short* __restrict__ QKV, const short* __restrict__ Vtg,
    float* __restrict__ Out) {
  // 36KB: K slots @0,8192; V slots @16384,24576; lsum @32768 (4KB).
  // Epilogue reuses @0..32768 as two 16KB O-partial regions.
  __shared__ char LB[36864];
  const int tid = threadIdx.x;
  const int lane = tid & 63, wid = tid >> 6;
  const int l15 = lane & 15, lg = lane >> 4;
  const int bh = blockIdx.x;
  const int qt = (S_ / 64 - 1) - (int)blockIdx.y;   // LPT: longest first
  const int b = bh >> 4, h = bh & 15;
  const int q0 = qt * 64;
  const short* Qg = QKV + (size_t)b * S_ * ND3 + h * DH_;
  const short* Kg = QKV + (size_t)b * S_ * ND3 + D_ + h * DH_;
  const short* Vg = Vtg + (size_t)bh * DH_ * S_;

  // staging (unchanged geometry)
  const int srow = tid >> 3;
  const int scol = ((tid & 7) ^ (srow & 7)) * 8;
  char* dst = LB + (tid & 192) * 16;
  // K fragment: rows kv = 16*wid + l15, d-chunk (ks*4+lg) ^ (row&7)
  int ka[2];
#pragma unroll
  for (int ks = 0; ks < 2; ++ks)
    ka[ks] = (wid * 16 + l15) * 128 + ((((ks * 4 + lg)) ^ (l15 & 7)) << 4);
  // V fragment (b64): row d = ntd*16+l15, kv chunk (2*wid + (lg>>1)) ^ (row&7)
  int va[4];
#pragma unroll
  for (int ntd = 0; ntd < 4; ++ntd)
    va[ntd] = (ntd * 16 + l15) * 128 +
              (((2 * wid + (lg >> 1)) ^ (l15 & 7)) << 4) + ((lg & 1) << 3);

  // Q fragments: 4 q-blocks x 2 ks (each lane: Q[qb*16+l15][ks*32+lg*8 ..+7])
  bf16x8 qf[4][2];
#pragma unroll
  for (int qb = 0; qb < 4; ++qb)
#pragma unroll
    for (int ks = 0; ks < 2; ++ks)
      qf[qb][ks] = *reinterpret_cast<const bf16x8*>(
          Qg + (size_t)(q0 + qb * 16 + l15) * ND3 + ks * 32 + lg * 8);

  const f32x4 cinit = (f32x4){SBIAS, SBIAS, SBIAS, SBIAS};

  f32x4 o[4][4];   // o[ntd][qb]: O[q=qb*16+l15][d=ntd*16+4*lg+r] kv-partial
#pragma unroll
  for (int i = 0; i < 4; ++i)
#pragma unroll
    for (int j = 0; j < 4; ++j) o[i][j] = (f32x4){0.f, 0.f, 0.f, 0.f};
  float lsum[4] = {0.f, 0.f, 0.f, 0.f};   // per-lane kv-partial, per q-block

  const short* kp = Kg + (size_t)srow * ND3 + scol;
  const short* vp = Vg + (size_t)srow * S_ + scol;

#define STAGE_AT(KOFF, VOFF)                                                  \
  {                                                                           \
    gl_lds16(kp, dst + (KOFF));                                               \
    gl_lds16(kp + 32 * ND3, dst + (KOFF) + 4096);                             \
    gl_lds16(vp, dst + (VOFF));                                               \
    gl_lds16(vp + 32 * S_, dst + (VOFF) + 4096);                              \
    kp += 64 * ND3;                                                           \
    vp += 64;                                                                 \
  }

// compute one kv-tile from slot parity SP; MASKED selects the diagonal path
#define COMPUTE(SP, MASKED, KV0)                                              \
  {                                                                           \
    const char* kb = LB + (SP) * 8192;                                        \
    const char* vb = LB + 16384 + (SP) * 8192;                                \
    const bf16x8 kf0 = *reinterpret_cast<const bf16x8*>(kb + ka[0]);          \
    const bf16x8 kf1 = *reinterpret_cast<const bf16x8*>(kb + ka[1]);          \
    f32x4 s[4];                                                               \
    _Pragma("unroll") for (int qb = 0; qb < 4; ++qb)                          \
        s[qb] = __builtin_amdgcn_mfma_f32_16x16x32_bf16(kf0, qf[qb][0],       \
                                                        cinit, 0, 0, 0);      \
    _Pragma("unroll") for (int qb = 0; qb < 4; ++qb)                          \
        s[qb] = __builtin_amdgcn_mfma_f32_16x16x32_bf16(kf1, qf[qb][1],       \
                                                        s[qb], 0, 0, 0);      \
    if (MASKED) { /* kv = KV0+16*wid+4*lg+r  vs  q = q0+qb*16+l15 */          \
      const int kvg = (KV0) + wid * 16 + lg * 4;                              \
      _Pragma("unroll") for (int qb = 0; qb < 4; ++qb)                        \
        _Pragma("unroll") for (int r = 0; r < 4; ++r)                         \
          if (kvg + r > q0 + qb * 16 + l15) s[qb][r] = MASKVAL;               \
    }                                                                         \
    bf16x4 pk[4];                                                             \
    _Pragma("unroll") for (int qb = 0; qb < 4; ++qb) {                        \
      const float p0 = EXP2(s[qb][0]);                                        \
      const float p1 = EXP2(s[qb][1]);                                        \
      const float p2 = EXP2(s[qb][2]);                                        \
      const float p3 = EXP2(s[qb][3]);                                        \
      lsum[qb] += (p0 + p1) + (p2 + p3);                                      \
      union { uint32_t u[2]; bf16x4 v; } pu;                                  \
      pu.u[0] = __builtin_amdgcn_perm(__float_as_uint(p1),                    \
                                      __float_as_uint(p0), 0x07060302u);      \
      pu.u[1] = __builtin_amdgcn_perm(__float_as_uint(p3),                    \
                                      __float_as_uint(p2), 0x07060302u);      \
      pk[qb] = pu.v;                                                          \
    }                                                                         \
    _Pragma("unroll") for (int ntd = 0; ntd < 4; ++ntd) {                     \
      const bf16x4 vf = *reinterpret_cast<const bf16x4*>(vb + va[ntd]);       \
      _Pragma("unroll") for (int qb = 0; qb < 4; ++qb)                        \
          o[ntd][qb] = __builtin_amdgcn_mfma_f32_16x16x16bf16_1k(             \
              vf, pk[qb], o[ntd][qb], 0, 0, 0);                               \
    }                                                                         \
  }

  // prologue: stage tile 0 into slot 0
  STAGE_AT(0, 16384);
  asm volatile("s_waitcnt vmcnt(0)" ::: "memory");
  __builtin_amdgcn_s_barrier();
  __builtin_amdgcn_sched_barrier(0);

  int sp = 0;
  for (int t = 0; t < qt; ++t) {
    STAGE_AT((sp ^ 1) * 8192, 16384 + (sp ^ 1) * 8192);  // stage tile t+1
    COMPUTE(sp, false, 0);
    asm volatile("s_waitcnt vmcnt(0)" ::: "memory");
    __builtin_amdgcn_s_barrier();
    __builtin_amdgcn_sched_barrier(0);
    sp ^= 1;
  }
  COMPUTE(sp, true, qt * 64);   // diagonal tile, masked (no stage/barrier)
#undef COMPUTE
#undef STAGE_AT

  // ---- epilogue: cross-wave reduction of O and lsum via LDS ----
  __builtin_amdgcn_s_barrier();   // all waves done reading K/V slots
  // lsum partials -> lsLDS[wid][qb][lane]
  float* lsLDS = reinterpret_cast<float*>(LB + 32768);
#pragma unroll
  for (int qb = 0; qb < 4; ++qb) lsLDS[wid * 256 + qb * 64 + lane] = lsum[qb];
  // O partials: wave 1 -> region0 (@0), wave 3 -> region1 (@16384)
#define OWRITE(RG)                                                            \
  _Pragma("unroll") for (int ntd = 0; ntd < 4; ++ntd)                         \
    _Pragma("unroll") for (int qb = 0; qb < 4; ++qb)                          \
        *reinterpret_cast<f32x4*>(LB + (RG) + ((ntd * 4 + qb) * 64 + lane) *  \
                                                  16) = o[ntd][qb];
#define OADD(RG)                                                              \
  _Pragma("unroll") for (int ntd = 0; ntd < 4; ++ntd)                         \
    _Pragma("unroll") for (int qb = 0; qb < 4; ++qb)                          \
        o[ntd][qb] += *reinterpret_cast<const f32x4*>(                        \
            LB + (RG) + ((ntd * 4 + qb) * 64 + lane) * 16);
  if (wid == 1) { OWRITE(0); }
  if (wid == 3) { OWRITE(16384); }
  __builtin_amdgcn_s_barrier();
  if (wid == 0) { OADD(0); }
  if (wid == 2) { OADD(16384); }
  __builtin_amdgcn_s_barrier();
  if (wid == 2) { OWRITE(0); }
  __builtin_amdgcn_s_barrier();
  if (wid == 0) {
    OADD(0);
#pragma unroll
    for (int qb = 0; qb < 4; ++qb) {
      float ls = lsLDS[0 * 256 + qb * 64 + lane] +
                 lsLDS[1 * 256 + qb * 64 + lane] +
                 lsLDS[2 * 256 + qb * 64 + lane] +
                 lsLDS[3 * 256 + qb * 64 + lane];
      ls += __shfl_xor(ls, 16);
      ls += __shfl_xor(ls, 32);
      const float inv = 1.f / ls;
      const int qrow = q0 + qb * 16 + l15;
#pragma unroll
      for (int ntd = 0; ntd < 4; ++ntd) {
        f32x4 v = {o[ntd][qb][0] * inv, o[ntd][qb][1] * inv,
                   o[ntd][qb][2] * inv, o[ntd][qb][3] * inv};
        *reinterpret_cast<f32x4*>(
            &Out[((size_t)b * S_ + qrow) * D_ + h * DH_ + ntd * 16 +
                 lg * 4]) = v;
      }
    }
  }
#undef OWRITE
#undef OADD
}

// ---------------------------------------------------------------- launcher
extern "C" void kernel_launch(void* const* d_in, const int* in_sizes, int n_in,
                              void* d_out, int out_size, void* d_ws,
                              size_t ws_size, hipStream_t stream) {
  const float* x  = (const float*)d_in[0];
  const float* Wq = (const float*)d_in[1];
  const float* bq = (const float*)d_in[2];
  const float* Wk = (const float*)d_in[3];
  const float* bk = (const float*)d_in[4];
  const float* Wv = (const float*)d_in[5];
  const float* bv = (const float*)d_in[6];
  float* out = (float*)d_out;

  char* ws = (char*)d_ws;
  short* xb  = (short*)(ws);             //  8 MB: [4096][1024] bf16
  short* Wt  = (short*)(ws + 8388608);   //  6 MB: [3072][1024] bf16
  short* qkv = (short*)(ws + 14680064);  // 24 MB: [4096][3072] bf16 (V unused)
  short* Vt  = (short*)(ws + 39845888);  //  8 MB: [32][64][2048] bf16 (plain T)

  prep_kernel<<<dim3(4096 + 3072), dim3(256), 0, stream>>>(x, Wq, Wk, Wv, xb,
                                                           Wt);
  qkv_gemm_kernel<<<dim3(256), dim3(512), 0, stream>>>(xb, Wt, bq, bk, bv,
                                                       qkv, Vt);
  attn_kernel<<<dim3(B_ * H_, S_ / 64), dim3(256), 0, stream>>>(qkv, Vt, out);
}

// Round 19
// 69.772 us; speedup vs baseline: 1.0607x; 1.0607x over previous
//
#include <hip/hip_runtime.h>
#include <hip/hip_bf16.h>
#include <stdint.h>

// Problem constants
#define B_    2
#define S_    2048
#define H_    16
#define DH_   64
#define D_    1024
#define ND3   3072      // 3*D
#define MTOT  4096      // B*S
#define L2E   1.4426950408889634f
#define MASKVAL (-3.0e38f)   // causal mask: exp2(MASKVAL) == 0
#define SBIAS   (-14.0f)     // static softmax offset (log2 units)

typedef __attribute__((ext_vector_type(8))) short bf16x8;
typedef __attribute__((ext_vector_type(4))) short bf16x4;
typedef __attribute__((ext_vector_type(4))) float f32x4;

// raw v_exp_f32 (no OCML denormal fixup; exact for normal range, and
// exp2(-3e38) == 0 as required by the mask path)
#if __has_builtin(__builtin_amdgcn_exp2f)
#define EXP2(x) __builtin_amdgcn_exp2f(x)
#else
#define EXP2(x) exp2f(x)
#endif

__device__ inline short f2bs(float f) {
  __hip_bfloat16 h = __float2bfloat16(f);
  return *reinterpret_cast<short*>(&h);
}

__device__ inline void gl_lds16(const void* g, void* l) {
  __builtin_amdgcn_global_load_lds(
      (const __attribute__((address_space(1))) uint32_t*)g,
      (__attribute__((address_space(3))) uint32_t*)l, 16, 0, 0);
}

// --------------------------------------- fused prep: x->bf16 and W->Wt bf16
__global__ __launch_bounds__(256) void prep_kernel(
    const float* __restrict__ X, const float* __restrict__ Wq,
    const float* __restrict__ Wk, const float* __restrict__ Wv,
    short* __restrict__ Xb, short* __restrict__ Wt) {
  __shared__ float t[32][33];
  int bid = blockIdx.x;
  if (bid < 4096) {
    const int i = (bid * 256 + threadIdx.x) * 4;
    float4 v = *reinterpret_cast<const float4*>(X + i);
    bf16x4 o;
    o[0] = f2bs(v.x); o[1] = f2bs(v.y); o[2] = f2bs(v.z); o[3] = f2bs(v.w);
    *reinterpret_cast<bf16x4*>(Xb + i) = o;
  } else {
    bid -= 4096;
    const int z = bid >> 10;             // 0..2 : Wq/Wk/Wv
    const int rem = bid & 1023;
    const int n0 = (rem & 31) * 32, k0 = (rem >> 5) * 32;
    const int x = threadIdx.x & 31, y = threadIdx.x >> 5;   // y in 0..7
    const float* W = z == 0 ? Wq : (z == 1 ? Wk : Wv);
    short* out = Wt + (size_t)z * (D_ * D_);
#pragma unroll
    for (int i = 0; i < 4; ++i)
      t[y + 8 * i][x] = W[(size_t)(k0 + y + 8 * i) * D_ + n0 + x];
    __syncthreads();
#pragma unroll
    for (int i = 0; i < 4; ++i)
      out[(size_t)(n0 + y + 8 * i) * D_ + k0 + x] = f2bs(t[x][y + 8 * i]);
  }
}

// ------------------------------------------------- QKV GEMM, 256x192 8-phase
// 256 blocks = 1/CU, all 7 staged pieces at P0/P1, single vmcnt(0) drain at
// P3-end, V epilogue writes kv-permuted Vt for b128 pair reads in attn.
__global__ __launch_bounds__(512, 2) void qkv_gemm_kernel(
    const short* __restrict__ Xb, const short* __restrict__ Wt,
    const float* __restrict__ bq, const float* __restrict__ bk,
    const float* __restrict__ bv, short* __restrict__ QKV,
    short* __restrict__ Vt) {
  __shared__ char Lds[114688];   // buf d: A @ d*57344 (32KB), B @ +32768 (24KB)
  const int tid = threadIdx.x;
  const int lane = tid & 63;
  const int wid = tid >> 6;
  const int l15 = lane & 15, lg = lane >> 4;
  const int wm = wid >> 2, wn = wid & 3;
  const int bid = blockIdx.x;
  const int wgid = (bid & 7) * 32 + (bid >> 3);
  const int m0 = (wgid >> 4) * 256, n0 = (wgid & 15) * 192;

  const int srow = tid >> 3;                         // 0..63
  const int scol = ((tid & 7) ^ (srow & 7)) * 8;
  const short* pa = Xb + (size_t)(m0 + srow) * D_ + scol;
  const short* pb = Wt + (size_t)(n0 + srow) * D_ + scol;
  char* sdst = Lds + (tid & 448) * 16;               // wave-uniform base

  const int abase = wm * 16384;                      // A rows wm*128..+127
  int a_off[8][2], b_off[3][2];
#pragma unroll
  for (int mr = 0; mr < 8; ++mr)
#pragma unroll
    for (int ks = 0; ks < 2; ++ks)
      a_off[mr][ks] =
          (mr * 16 + l15) * 128 + ((((ks * 4 + lg)) ^ (l15 & 7)) << 4);
#pragma unroll
  for (int nr = 0; nr < 3; ++nr)
#pragma unroll
    for (int ks = 0; ks < 2; ++ks)
      b_off[nr][ks] = (wn * 48 + nr * 16 + l15) * 128 +
                      ((((ks * 4 + lg)) ^ (l15 & 7)) << 4);

  f32x4 acc[8][3];
#pragma unroll
  for (int i = 0; i < 8; ++i)
#pragma unroll
    for (int j = 0; j < 3; ++j) acc[i][j] = (f32x4){0.f, 0.f, 0.f, 0.f};

#define BARRIER()                                                             \
  __builtin_amdgcn_s_barrier();                                               \
  __builtin_amdgcn_sched_barrier(0)

  gl_lds16(pa, sdst);
  gl_lds16(pa + (size_t)64 * D_, sdst + 8192);
  gl_lds16(pa + (size_t)128 * D_, sdst + 16384);
  gl_lds16(pa + (size_t)192 * D_, sdst + 24576);
  gl_lds16(pb, sdst + 32768);
  gl_lds16(pb + (size_t)64 * D_, sdst + 40960);
  gl_lds16(pb + (size_t)128 * D_, sdst + 49152);
  asm volatile("s_waitcnt vmcnt(0)" ::: "memory");
  BARRIER();

#define TILE(J, DL)                                                           \
  {                                                                           \
    const int j_ = (J);                                                       \
    const bool stg = (j_ + 1 < 16);                                           \
    const int RD = (DL) * 57344;                                              \
    const int WD = (1 - (DL)) * 57344;                                        \
    const short* pa1 = pa + (j_ + 1) * 64;                                    \
    const short* pb1 = pb + (j_ + 1) * 64;                                    \
    bf16x8 af[4], bf0, bf1, bf2;                                              \
    /* P0: stage A-lo + B0,B1; frags B ks0 + A ks0 mr0-3; MFMA acc[0..3] */   \
    if (stg) {                                                                \
      gl_lds16(pa1, sdst + WD);                                               \
      gl_lds16(pa1 + (size_t)64 * D_, sdst + WD + 8192);                      \
      gl_lds16(pb1, sdst + WD + 32768);                                       \
      gl_lds16(pb1 + (size_t)64 * D_, sdst + WD + 40960);                     \
    }                                                                         \
    bf0 = *reinterpret_cast<const bf16x8*>(Lds + RD + 32768 + b_off[0][0]);   \
    bf1 = *reinterpret_cast<const bf16x8*>(Lds + RD + 32768 + b_off[1][0]);   \
    bf2 = *reinterpret_cast<const bf16x8*>(Lds + RD + 32768 + b_off[2][0]);   \
    _Pragma("unroll") for (int mr = 0; mr < 4; ++mr) af[mr] =                 \
        *reinterpret_cast<const bf16x8*>(Lds + RD + abase + a_off[mr][0]);    \
    BARRIER();                                                                \
    __builtin_amdgcn_s_setprio(1);                                            \
    _Pragma("unroll") for (int mr = 0; mr < 4; ++mr) {                        \
      acc[mr][0] = __builtin_amdgcn_mfma_f32_16x16x32_bf16(af[mr], bf0,       \
                                                           acc[mr][0], 0, 0,  \
                                                           0);                \
      acc[mr][1] = __builtin_amdgcn_mfma_f32_16x16x32_bf16(af[mr], bf1,       \
                                                           acc[mr][1], 0, 0,  \
                                                           0);                \
      acc[mr][2] = __builtin_amdgcn_mfma_f32_16x16x32_bf16(af[mr], bf2,       \
                                                           acc[mr][2], 0, 0,  \
                                                           0);                \
    }                                                                         \
    __builtin_amdgcn_s_setprio(0);                                            \
    BARRIER();                                                                \
    /* P1: stage A-hi + B2; frags A ks0 mr4-7; MFMA acc[4..7] */              \
    if (stg) {                                                                \
      gl_lds16(pa1 + (size_t)128 * D_, sdst + WD + 16384);                    \
      gl_lds16(pa1 + (size_t)192 * D_, sdst + WD + 24576);                    \
      gl_lds16(pb1 + (size_t)128 * D_, sdst + WD + 49152);                    \
    }                                                                         \
    _Pragma("unroll") for (int mr = 0; mr < 4; ++mr) af[mr] =                 \
        *reinterpret_cast<const bf16x8*>(Lds + RD + abase +                   \
                                         a_off[mr + 4][0]);                   \
    BARRIER();                                                                \
    __builtin_amdgcn_s_setprio(1);                                            \
    _Pragma("unroll") for (int mr = 0; mr < 4; ++mr) {                        \
      acc[mr + 4][0] = __builtin_amdgcn_mfma_f32_16x16x32_bf16(               \
          af[mr], bf0, acc[mr + 4][0], 0, 0, 0);                              \
      acc[mr + 4][1] = __builtin_amdgcn_mfma_f32_16x16x32_bf16(               \
          af[mr], bf1, acc[mr + 4][1], 0, 0, 0);                              \
      acc[mr + 4][2] = __builtin_amdgcn_mfma_f32_16x16x32_bf16(               \
          af[mr], bf2, acc[mr + 4][2], 0, 0, 0);                              \
    }                                                                         \
    __builtin_amdgcn_s_setprio(0);                                            \
    BARRIER();                                                                \
    /* P2: frags B ks1 + A ks1 mr0-3; MFMA acc[0..3] */                       \
    bf0 = *reinterpret_cast<const bf16x8*>(Lds + RD + 32768 + b_off[0][1]);   \
    bf1 = *reinterpret_cast<const bf16x8*>(Lds + RD + 32768 + b_off[1][1]);   \
    bf2 = *reinterpret_cast<const bf16x8*>(Lds + RD + 32768 + b_off[2][1]);   \
    _Pragma("unroll") for (int mr = 0; mr < 4; ++mr) af[mr] =                 \
        *reinterpret_cast<const bf16x8*>(Lds + RD + abase + a_off[mr][1]);    \
    BARRIER();                                                                \
    __builtin_amdgcn_s_setprio(1);                                            \
    _Pragma("unroll") for (int mr = 0; mr < 4; ++mr) {                        \
      acc[mr][0] = __builtin_amdgcn_mfma_f32_16x16x32_bf16(af[mr], bf0,       \
                                                           acc[mr][0], 0, 0,  \
                                                           0);                \
      acc[mr][1] = __builtin_amdgcn_mfma_f32_16x16x32_bf16(af[mr], bf1,       \
                                                           acc[mr][1], 0, 0,  \
                                                           0);                \
      acc[mr][2] = __builtin_amdgcn_mfma_f32_16x16x32_bf16(af[mr], bf2,       \
                                                           acc[mr][2], 0, 0,  \
                                                           0);                \
    }                                                                         \
    __builtin_amdgcn_s_setprio(0);                                            \
    BARRIER();                                                                \
    /* P3: frags A ks1 mr4-7; MFMA acc[4..7]; drain staged loads */           \
    _Pragma("unroll") for (int mr = 0; mr < 4; ++mr) af[mr] =                 \
        *reinterpret_cast<const bf16x8*>(Lds + RD + abase +                   \
                                         a_off[mr + 4][1]);                   \
    BARRIER();                                                                \
    __builtin_amdgcn_s_setprio(1);                                            \
    _Pragma("unroll") for (int mr = 0; mr < 4; ++mr) {                        \
      acc[mr + 4][0] = __builtin_amdgcn_mfma_f32_16x16x32_bf16(               \
          af[mr], bf0, acc[mr + 4][0], 0, 0, 0);                              \
      acc[mr + 4][1] = __builtin_amdgcn_mfma_f32_16x16x32_bf16(               \
          af[mr], bf1, acc[mr + 4][1], 0, 0, 0);                              \
      acc[mr + 4][2] = __builtin_amdgcn_mfma_f32_16x16x32_bf16(               \
          af[mr], bf2, acc[mr + 4][2], 0, 0, 0);                              \
    }                                                                         \
    __builtin_amdgcn_s_setprio(0);                                            \
    asm volatile("s_waitcnt vmcnt(0)" ::: "memory");                          \
    BARRIER();                                                                \
  }

  for (int jj = 0; jj < 16; jj += 2) {
    TILE(jj, 0);
    TILE(jj + 1, 1);
  }
#undef TILE
#undef BARRIER

  const int wr = wm * 128;
#pragma unroll
  for (int nr = 0; nr < 3; ++nr) {
    const int col = n0 + wn * 48 + nr * 16 + l15;
    if (col < 2 * D_) {  // Q or K -> qkv rows
      float bias, qs;
      if (col < D_) { bias = bq[col];      qs = 0.125f * L2E; }
      else          { bias = bk[col - D_]; qs = 1.f; }
#pragma unroll
      for (int mr = 0; mr < 8; ++mr)
#pragma unroll
        for (int r = 0; r < 4; ++r) {
          const int row = m0 + wr + mr * 16 + lg * 4 + r;
          QKV[(size_t)row * ND3 + col] = f2bs((acc[mr][nr][r] + bias) * qs);
        }
    } else {  // V -> Vt[bh][dh][s], kv-permuted for b128 pair reads in attn
      const int f = col - 2 * D_;                    // v-feature 0..1023
      const float bias = bv[f];
      const int base0 = (m0 & 2047) + wr;            // multiple of 64
      short* vout = Vt + ((size_t)((m0 >> 11) * H_ + (f >> 6)) * DH_ +
                          (f & 63)) * S_;
#pragma unroll
      for (int mr = 0; mr < 8; ++mr) {
        bf16x4 pv;
#pragma unroll
        for (int r = 0; r < 4; ++r) pv[r] = f2bs(acc[mr][nr][r] + bias);
        const int ntk = mr & 3;
        const int s_new = base0 + (mr >> 2) * 64 +
                          ((ntk >> 1) * 4 + lg) * 8 + (ntk & 1) * 4;
        *reinterpret_cast<bf16x4*>(vout + s_new) = pv;
      }
    }
  }
}

// ----------------------------------------------------------- flash attention
// r17 attn verbatim (best measured ~33 us): q-split waves, static-offset
// softmax (SBIAS in a constant C register), raw v_exp_f32, v_perm_b32 pack,
// V read as b128 pairs (kv-permuted Vt), 2K+3V LDS slots (40KB), 4 blocks/CU,
// QK one tile ahead, raw barrier + vmcnt drain, XOR-swizzled staging, LPT.
__global__ __launch_bounds__(256, 4) void attn_kernel(
    const short* __restrict__ QKV, const short* __restrict__ Vtg,
    float* __restrict__ Out) {
  __shared__ short KV[5][4096];   // 40KB: K slots @0,8192; V @16384/24576/32768
  const int tid = threadIdx.x;
  const int lane = tid & 63, wid = tid >> 6;
  const int l15 = lane & 15, lg = lane >> 4;
  const int bh = blockIdx.x;
  const int qt = (S_ / 64 - 1) - (int)blockIdx.y;   // LPT: longest first
  const int b = bh >> 4, h = bh & 15;
  const int q0 = qt * 64;
  const short* Qg = QKV + (size_t)b * S_ * ND3 + h * DH_;
  const short* Kg = QKV + (size_t)b * S_ * ND3 + D_ + h * DH_;
  const short* Vg = Vtg + (size_t)bh * DH_ * S_;

  const int srow = tid >> 3;
  const int scol = ((tid & 7) ^ (srow & 7)) * 8;
  const char* kbase = (const char*)&KV[0][0];
  char* dst = (char*)kbase + (tid & 192) * 16;
  int ka[2];
#pragma unroll
  for (int ks = 0; ks < 2; ++ks)
    ka[ks] = l15 * 128 + ((((ks * 4 + lg)) ^ (l15 & 7)) << 4);
  const int qrow_g = q0 + wid * 16 + l15;

  bf16x8 qf[2];
#pragma unroll
  for (int ks = 0; ks < 2; ++ks)
    qf[ks] = *reinterpret_cast<const bf16x8*>(Qg + (size_t)qrow_g * ND3 +
                                              ks * 32 + lg * 8);

  const f32x4 cinit = (f32x4){SBIAS, SBIAS, SBIAS, SBIAS};  // constant C reg

  f32x4 o[4];
#pragma unroll
  for (int i = 0; i < 4; ++i) o[i] = (f32x4){0.f, 0.f, 0.f, 0.f};
  float lsum = 0.f;

  const short* kp = Kg + (size_t)srow * ND3 + scol;
  const short* vp = Vg + (size_t)srow * S_ + scol;

#define STAGE_AT(KOFF, VOFF)                                                  \
  {                                                                           \
    gl_lds16(kp, dst + (KOFF));                                               \
    gl_lds16(kp + 32 * ND3, dst + (KOFF) + 4096);                             \
    gl_lds16(vp, dst + (VOFF));                                               \
    gl_lds16(vp + 32 * S_, dst + (VOFF) + 4096);                              \
    kp += 64 * ND3;                                                           \
    vp += 64;                                                                 \
  }

  int kr = 8192, kw = 0;
  int vr = 16384, vw = 32768;          // VSUM = 73728

  STAGE_AT(0, 16384);
  if (qt >= 1) STAGE_AT(8192, 24576);
  asm volatile("s_waitcnt vmcnt(0)" ::: "memory");
  __builtin_amdgcn_s_barrier();
  __builtin_amdgcn_sched_barrier(0);

  f32x4 sA[4], sB[4];
#pragma unroll
  for (int nt = 0; nt < 4; ++nt)
    sA[nt] = __builtin_amdgcn_mfma_f32_16x16x32_bf16(
        *reinterpret_cast<const bf16x8*>(kbase + ka[0] + nt * 2048), qf[0],
        cinit, 0, 0, 0);
#pragma unroll
  for (int nt = 0; nt < 4; ++nt)
    sA[nt] = __builtin_amdgcn_mfma_f32_16x16x32_bf16(
        *reinterpret_cast<const bf16x8*>(kbase + ka[1] + nt * 2048), qf[1],
        sA[nt], 0, 0, 0);

#define STEP_BODY(T, SC, SN)                                                  \
  {                                                                           \
    const int T_ = (T);                                                       \
    if (T_ + 2 <= qt) STAGE_AT(kw, vw);                                       \
    if (T_ + 1 <= qt) {                                                       \
      _Pragma("unroll") for (int nt = 0; nt < 4; ++nt)                        \
          SN[nt] = __builtin_amdgcn_mfma_f32_16x16x32_bf16(                   \
              *reinterpret_cast<const bf16x8*>(kbase + kr + ka[0] +           \
                                               nt * 2048),                    \
              qf[0], cinit, 0, 0, 0);                                         \
      _Pragma("unroll") for (int nt = 0; nt < 4; ++nt)                        \
          SN[nt] = __builtin_amdgcn_mfma_f32_16x16x32_bf16(                   \
              *reinterpret_cast<const bf16x8*>(kbase + kr + ka[1] +           \
                                               nt * 2048),                    \
              qf[1], SN[nt], 0, 0, 0);                                        \
    }                                                                         \
    if (T_ == qt) { /* causal mask on diagonal tile */                        \
      const int kv0 = T_ * 64;                                                \
      _Pragma("unroll") for (int nt = 0; nt < 4; ++nt)                        \
        _Pragma("unroll") for (int r = 0; r < 4; ++r)                         \
          if (kv0 + nt * 16 + lg * 4 + r > qrow_g) SC[nt][r] = MASKVAL;       \
    }                                                                         \
    float rowsum = 0.f;                                                       \
    bf16x4 pk[4];                                                             \
    _Pragma("unroll") for (int nt = 0; nt < 4; ++nt) {                        \
      const float p0 = EXP2(SC[nt][0]);                                       \
      const float p1 = EXP2(SC[nt][1]);                                       \
      const float p2 = EXP2(SC[nt][2]);                                       \
      const float p3 = EXP2(SC[nt][3]);                                       \
      rowsum += (p0 + p1) + (p2 + p3);                                        \
      union { uint32_t u[2]; bf16x4 v; } pu;                                  \
      pu.u[0] = __builtin_amdgcn_perm(__float_as_uint(p1),                    \
                                      __float_as_uint(p0), 0x07060302u);      \
      pu.u[1] = __builtin_amdgcn_perm(__float_as_uint(p3),                    \
                                      __float_as_uint(p2), 0x07060302u);      \
      pk[nt] = pu.v;                                                          \
    }                                                                         \
    lsum += rowsum;                                                           \
    _Pragma("unroll") for (int p = 0; p < 2; ++p)                             \
      _Pragma("unroll") for (int ntd = 0; ntd < 4; ++ntd) {                   \
        const bf16x8 vf8 = *reinterpret_cast<const bf16x8*>(                  \
            kbase + vr + ka[p] + ntd * 2048);                                 \
        const bf16x4 vlo = __builtin_shufflevector(vf8, vf8, 0, 1, 2, 3);     \
        const bf16x4 vhi = __builtin_shufflevector(vf8, vf8, 4, 5, 6, 7);     \
        o[ntd] = __builtin_amdgcn_mfma_f32_16x16x16bf16_1k(vlo, pk[2 * p],    \
                                                           o[ntd], 0, 0, 0);  \
        o[ntd] = __builtin_amdgcn_mfma_f32_16x16x16bf16_1k(                   \
            vhi, pk[2 * p + 1], o[ntd], 0, 0, 0);                             \
      }                                                                       \
    if (T_ < qt) {                                                            \
      asm volatile("s_waitcnt vmcnt(0)" ::: "memory");                        \
      __builtin_amdgcn_s_barrier();                                           \
      __builtin_amdgcn_sched_barrier(0);                                      \
    }                                                                         \
    kr ^= 8192; kw ^= 8192;                                                   \
    { const int tv = vr; vr = 73728 - vr - vw; vw = tv; }                     \
  }

  for (int t = 0; t <= qt; t += 2) {
    STEP_BODY(t, sA, sB);
    if (t + 1 <= qt) STEP_BODY(t + 1, sB, sA);
  }
#undef STEP_BODY
#undef STAGE_AT

  float ls = lsum;
  ls += __shfl_xor(ls, 16);
  ls += __shfl_xor(ls, 32);
  const float inv = 1.f / ls;
#pragma unroll
  for (int nt = 0; nt < 4; ++nt) {
    f32x4 v = {o[nt][0] * inv, o[nt][1] * inv, o[nt][2] * inv, o[nt][3] * inv};
    *reinterpret_cast<f32x4*>(
        &Out[((size_t)b * S_ + qrow_g) * D_ + h * DH_ + nt * 16 + lg * 4]) = v;
  }
}

// ---------------------------------------------------------------- launcher
extern "C" void kernel_launch(void* const* d_in, const int* in_sizes, int n_in,
                              void* d_out, int out_size, void* d_ws,
                              size_t ws_size, hipStream_t stream) {
  const float* x  = (const float*)d_in[0];
  const float* Wq = (const float*)d_in[1];
  const float* bq = (const float*)d_in[2];
  const float* Wk = (const float*)d_in[3];
  const float* bk = (const float*)d_in[4];
  const float* Wv = (const float*)d_in[5];
  const float* bv = (const float*)d_in[6];
  float* out = (float*)d_out;

  char* ws = (char*)d_ws;
  short* xb  = (short*)(ws);             //  8 MB: [4096][1024] bf16
  short* Wt  = (short*)(ws + 8388608);   //  6 MB: [3072][1024] bf16
  short* qkv = (short*)(ws + 14680064);  // 24 MB: [4096][3072] bf16 (V unused)
  short* Vt  = (short*)(ws + 39845888);  //  8 MB: [32][64][2048] bf16 (kv-permuted)

  prep_kernel<<<dim3(4096 + 3072), dim3(256), 0, stream>>>(x, Wq, Wk, Wv, xb,
                                                           Wt);
  qkv_gemm_kernel<<<dim3(256), dim3(512), 0, stream>>>(xb, Wt, bq, bk, bv,
                                                       qkv, Vt);
  attn_kernel<<<dim3(B_ * H_, S_ / 64), dim3(256), 0, stream>>>(qkv, Vt, out);
}

// Round 20
// 68.937 us; speedup vs baseline: 1.0736x; 1.0121x over previous
//
#include <hip/hip_runtime.h>
#include <hip/hip_bf16.h>
#include <stdint.h>

// Problem constants
#define B_    2
#define S_    2048
#define H_    16
#define DH_   64
#define D_    1024
#define ND3   3072      // 3*D
#define MTOT  4096      // B*S
#define L2E   1.4426950408889634f
#define MASKVAL (-3.0e38f)   // causal mask: exp2(MASKVAL) == 0
#define SBIAS   (-14.0f)     // static softmax offset (log2 units)

typedef __attribute__((ext_vector_type(8))) short bf16x8;
typedef __attribute__((ext_vector_type(4))) short bf16x4;
typedef __attribute__((ext_vector_type(4))) float f32x4;

// raw v_exp_f32 (no OCML denormal fixup; exact for normal range, and
// exp2(-3e38) == 0 as required by the mask path)
#if __has_builtin(__builtin_amdgcn_exp2f)
#define EXP2(x) __builtin_amdgcn_exp2f(x)
#else
#define EXP2(x) exp2f(x)
#endif

__device__ inline short f2bs(float f) {
  __hip_bfloat16 h = __float2bfloat16(f);
  return *reinterpret_cast<short*>(&h);
}

__device__ inline void gl_lds16(const void* g, void* l) {
  __builtin_amdgcn_global_load_lds(
      (const __attribute__((address_space(1))) uint32_t*)g,
      (__attribute__((address_space(3))) uint32_t*)l, 16, 0, 0);
}

// --------------------------------------- fused prep: x->bf16 and W->Wt bf16
__global__ __launch_bounds__(256) void prep_kernel(
    const float* __restrict__ X, const float* __restrict__ Wq,
    const float* __restrict__ Wk, const float* __restrict__ Wv,
    short* __restrict__ Xb, short* __restrict__ Wt) {
  __shared__ float t[32][33];
  int bid = blockIdx.x;
  if (bid < 4096) {
    const int i = (bid * 256 + threadIdx.x) * 4;
    float4 v = *reinterpret_cast<const float4*>(X + i);
    bf16x4 o;
    o[0] = f2bs(v.x); o[1] = f2bs(v.y); o[2] = f2bs(v.z); o[3] = f2bs(v.w);
    *reinterpret_cast<bf16x4*>(Xb + i) = o;
  } else {
    bid -= 4096;
    const int z = bid >> 10;             // 0..2 : Wq/Wk/Wv
    const int rem = bid & 1023;
    const int n0 = (rem & 31) * 32, k0 = (rem >> 5) * 32;
    const int x = threadIdx.x & 31, y = threadIdx.x >> 5;   // y in 0..7
    const float* W = z == 0 ? Wq : (z == 1 ? Wk : Wv);
    short* out = Wt + (size_t)z * (D_ * D_);
#pragma unroll
    for (int i = 0; i < 4; ++i)
      t[y + 8 * i][x] = W[(size_t)(k0 + y + 8 * i) * D_ + n0 + x];
    __syncthreads();
#pragma unroll
    for (int i = 0; i < 4; ++i)
      out[(size_t)(n0 + y + 8 * i) * D_ + k0 + x] = f2bs(t[x][y + 8 * i]);
  }
}

// ------------------------------------------------- QKV GEMM, 256x192 8-phase
// 256 blocks = 1/CU, all 7 staged pieces at P0/P1, single vmcnt(0) drain at
// P3-end, V epilogue writes kv-permuted Vt for b128 pair reads in attn.
// r20: Q/K epilogue bounces through the (now-dead) LDS so global stores are
// coalesced b128 chunks (12/thread) instead of 96 scalar 2B stores per lane.
__global__ __launch_bounds__(512, 2) void qkv_gemm_kernel(
    const short* __restrict__ Xb, const short* __restrict__ Wt,
    const float* __restrict__ bq, const float* __restrict__ bk,
    const float* __restrict__ bv, short* __restrict__ QKV,
    short* __restrict__ Vt) {
  __shared__ char Lds[114688];   // buf d: A @ d*57344 (32KB), B @ +32768 (24KB)
  const int tid = threadIdx.x;
  const int lane = tid & 63;
  const int wid = tid >> 6;
  const int l15 = lane & 15, lg = lane >> 4;
  const int wm = wid >> 2, wn = wid & 3;
  const int bid = blockIdx.x;
  const int wgid = (bid & 7) * 32 + (bid >> 3);
  const int m0 = (wgid >> 4) * 256, n0 = (wgid & 15) * 192;

  const int srow = tid >> 3;                         // 0..63
  const int scol = ((tid & 7) ^ (srow & 7)) * 8;
  const short* pa = Xb + (size_t)(m0 + srow) * D_ + scol;
  const short* pb = Wt + (size_t)(n0 + srow) * D_ + scol;
  char* sdst = Lds + (tid & 448) * 16;               // wave-uniform base

  const int abase = wm * 16384;                      // A rows wm*128..+127
  int a_off[8][2], b_off[3][2];
#pragma unroll
  for (int mr = 0; mr < 8; ++mr)
#pragma unroll
    for (int ks = 0; ks < 2; ++ks)
      a_off[mr][ks] =
          (mr * 16 + l15) * 128 + ((((ks * 4 + lg)) ^ (l15 & 7)) << 4);
#pragma unroll
  for (int nr = 0; nr < 3; ++nr)
#pragma unroll
    for (int ks = 0; ks < 2; ++ks)
      b_off[nr][ks] = (wn * 48 + nr * 16 + l15) * 128 +
                      ((((ks * 4 + lg)) ^ (l15 & 7)) << 4);

  f32x4 acc[8][3];
#pragma unroll
  for (int i = 0; i < 8; ++i)
#pragma unroll
    for (int j = 0; j < 3; ++j) acc[i][j] = (f32x4){0.f, 0.f, 0.f, 0.f};

#define BARRIER()                                                             \
  __builtin_amdgcn_s_barrier();                                               \
  __builtin_amdgcn_sched_barrier(0)

  gl_lds16(pa, sdst);
  gl_lds16(pa + (size_t)64 * D_, sdst + 8192);
  gl_lds16(pa + (size_t)128 * D_, sdst + 16384);
  gl_lds16(pa + (size_t)192 * D_, sdst + 24576);
  gl_lds16(pb, sdst + 32768);
  gl_lds16(pb + (size_t)64 * D_, sdst + 40960);
  gl_lds16(pb + (size_t)128 * D_, sdst + 49152);
  asm volatile("s_waitcnt vmcnt(0)" ::: "memory");
  BARRIER();

#define TILE(J, DL)                                                           \
  {                                                                           \
    const int j_ = (J);                                                       \
    const bool stg = (j_ + 1 < 16);                                           \
    const int RD = (DL) * 57344;                                              \
    const int WD = (1 - (DL)) * 57344;                                        \
    const short* pa1 = pa + (j_ + 1) * 64;                                    \
    const short* pb1 = pb + (j_ + 1) * 64;                                    \
    bf16x8 af[4], bf0, bf1, bf2;                                              \
    /* P0: stage A-lo + B0,B1; frags B ks0 + A ks0 mr0-3; MFMA acc[0..3] */   \
    if (stg) {                                                                \
      gl_lds16(pa1, sdst + WD);                                               \
      gl_lds16(pa1 + (size_t)64 * D_, sdst + WD + 8192);                      \
      gl_lds16(pb1, sdst + WD + 32768);                                       \
      gl_lds16(pb1 + (size_t)64 * D_, sdst + WD + 40960);                     \
    }                                                                         \
    bf0 = *reinterpret_cast<const bf16x8*>(Lds + RD + 32768 + b_off[0][0]);   \
    bf1 = *reinterpret_cast<const bf16x8*>(Lds + RD + 32768 + b_off[1][0]);   \
    bf2 = *reinterpret_cast<const bf16x8*>(Lds + RD + 32768 + b_off[2][0]);   \
    _Pragma("unroll") for (int mr = 0; mr < 4; ++mr) af[mr] =                 \
        *reinterpret_cast<const bf16x8*>(Lds + RD + abase + a_off[mr][0]);    \
    BARRIER();                                                                \
    __builtin_amdgcn_s_setprio(1);                                            \
    _Pragma("unroll") for (int mr = 0; mr < 4; ++mr) {                        \
      acc[mr][0] = __builtin_amdgcn_mfma_f32_16x16x32_bf16(af[mr], bf0,       \
                                                           acc[mr][0], 0, 0,  \
                                                           0);                \
      acc[mr][1] = __builtin_amdgcn_mfma_f32_16x16x32_bf16(af[mr], bf1,       \
                                                           acc[mr][1], 0, 0,  \
                                                           0);                \
      acc[mr][2] = __builtin_amdgcn_mfma_f32_16x16x32_bf16(af[mr], bf2,       \
                                                           acc[mr][2], 0, 0,  \
                                                           0);                \
    }                                                                         \
    __builtin_amdgcn_s_setprio(0);                                            \
    BARRIER();                                                                \
    /* P1: stage A-hi + B2; frags A ks0 mr4-7; MFMA acc[4..7] */              \
    if (stg) {                                                                \
      gl_lds16(pa1 + (size_t)128 * D_, sdst + WD + 16384);                    \
      gl_lds16(pa1 + (size_t)192 * D_, sdst + WD + 24576);                    \
      gl_lds16(pb1 + (size_t)128 * D_, sdst + WD + 49152);                    \
    }                                                                         \
    _Pragma("unroll") for (int mr = 0; mr < 4; ++mr) af[mr] =                 \
        *reinterpret_cast<const bf16x8*>(Lds + RD + abase +                   \
                                         a_off[mr + 4][0]);                   \
    BARRIER();                                                                \
    __builtin_amdgcn_s_setprio(1);                                            \
    _Pragma("unroll") for (int mr = 0; mr < 4; ++mr) {                        \
      acc[mr + 4][0] = __builtin_amdgcn_mfma_f32_16x16x32_bf16(               \
          af[mr], bf0, acc[mr + 4][0], 0, 0, 0);                              \
      acc[mr + 4][1] = __builtin_amdgcn_mfma_f32_16x16x32_bf16(               \
          af[mr], bf1, acc[mr + 4][1], 0, 0, 0);                              \
      acc[mr + 4][2] = __builtin_amdgcn_mfma_f32_16x16x32_bf16(               \
          af[mr], bf2, acc[mr + 4][2], 0, 0, 0);                              \
    }                                                                         \
    __builtin_amdgcn_s_setprio(0);                                            \
    BARRIER();                                                                \
    /* P2: frags B ks1 + A ks1 mr0-3; MFMA acc[0..3] */                       \
    bf0 = *reinterpret_cast<const bf16x8*>(Lds + RD + 32768 + b_off[0][1]);   \
    bf1 = *reinterpret_cast<const bf16x8*>(Lds + RD + 32768 + b_off[1][1]);   \
    bf2 = *reinterpret_cast<const bf16x8*>(Lds + RD + 32768 + b_off[2][1]);   \
    _Pragma("unroll") for (int mr = 0; mr < 4; ++mr) af[mr] =                 \
        *reinterpret_cast<const bf16x8*>(Lds + RD + abase + a_off[mr][1]);    \
    BARRIER();                                                                \
    __builtin_amdgcn_s_setprio(1);                                            \
    _Pragma("unroll") for (int mr = 0; mr < 4; ++mr) {                        \
      acc[mr][0] = __builtin_amdgcn_mfma_f32_16x16x32_bf16(af[mr], bf0,       \
                                                           acc[mr][0], 0, 0,  \
                                                           0);                \
      acc[mr][1] = __builtin_amdgcn_mfma_f32_16x16x32_bf16(af[mr], bf1,       \
                                                           acc[mr][1], 0, 0,  \
                                                           0);                \
      acc[mr][2] = __builtin_amdgcn_mfma_f32_16x16x32_bf16(af[mr], bf2,       \
                                                           acc[mr][2], 0, 0,  \
                                                           0);                \
    }                                                                         \
    __builtin_amdgcn_s_setprio(0);                                            \
    BARRIER();                                                                \
    /* P3: frags A ks1 mr4-7; MFMA acc[4..7]; drain staged loads */           \
    _Pragma("unroll") for (int mr = 0; mr < 4; ++mr) af[mr] =                 \
        *reinterpret_cast<const bf16x8*>(Lds + RD + abase +                   \
                                         a_off[mr + 4][1]);                   \
    BARRIER();                                                                \
    __builtin_amdgcn_s_setprio(1);                                            \
    _Pragma("unroll") for (int mr = 0; mr < 4; ++mr) {                        \
      acc[mr + 4][0] = __builtin_amdgcn_mfma_f32_16x16x32_bf16(               \
          af[mr], bf0, acc[mr + 4][0], 0, 0, 0);                              \
      acc[mr + 4][1] = __builtin_amdgcn_mfma_f32_16x16x32_bf16(               \
          af[mr], bf1, acc[mr + 4][1], 0, 0, 0);                              \
      acc[mr + 4][2] = __builtin_amdgcn_mfma_f32_16x16x32_bf16(               \
          af[mr], bf2, acc[mr + 4][2], 0, 0, 0);                              \
    }                                                                         \
    __builtin_amdgcn_s_setprio(0);                                            \
    asm volatile("s_waitcnt vmcnt(0)" ::: "memory");                          \
    BARRIER();                                                                \
  }

  for (int jj = 0; jj < 16; jj += 2) {
    TILE(jj, 0);
    TILE(jj + 1, 1);
  }
#undef TILE
#undef BARRIER

  // ---- epilogue ----
  const int wr = wm * 128;
  // number of Q/K columns in this block's 192-col range (rest are V)
  const int nqk = (n0 >= 2 * D_) ? 0
                  : ((2 * D_ - n0 < 192) ? (2 * D_ - n0) : 192);

  // V columns: per-lane kv-permuted b64 stores (unchanged)
#pragma unroll
  for (int nr = 0; nr < 3; ++nr) {
    const int c = wn * 48 + nr * 16 + l15;         // local col
    if (c >= nqk) {
      const int f = n0 + c - 2 * D_;               // v-feature 0..1023
      const float bias = bv[f];
      const int base0 = (m0 & 2047) + wr;          // multiple of 64
      short* vout = Vt + ((size_t)((m0 >> 11) * H_ + (f >> 6)) * DH_ +
                          (f & 63)) * S_;
#pragma unroll
      for (int mr = 0; mr < 8; ++mr) {
        bf16x4 pv;
#pragma unroll
        for (int r = 0; r < 4; ++r) pv[r] = f2bs(acc[mr][nr][r] + bias);
        const int ntk = mr & 3;
        const int s_new = base0 + (mr >> 2) * 64 +
                          ((ntk >> 1) * 4 + lg) * 8 + (ntk & 1) * 4;
        *reinterpret_cast<bf16x4*>(vout + s_new) = pv;
      }
    }
  }

  // Q/K columns: bounce through LDS (dead after the K-loop; the trailing
  // block-wide barrier guarantees all LDS reads are done) so the global
  // stores become coalesced b128 chunks. LDS tile: bf16 [256][c], row
  // stride 400 B (16B-aligned; breaks the 4-row lg-group bank collision).
  if (nqk > 0) {
#pragma unroll
    for (int nr = 0; nr < 3; ++nr) {
      const int c = wn * 48 + nr * 16 + l15;
      if (c < nqk) {                               // wave-uniform (x16 bounds)
        const int col = n0 + c;
        float bias, qs;
        if (col < D_) { bias = bq[col];      qs = 0.125f * L2E; }
        else          { bias = bk[col - D_]; qs = 1.f; }
#pragma unroll
        for (int mr = 0; mr < 8; ++mr)
#pragma unroll
          for (int r = 0; r < 4; ++r) {
            const int m = wr + mr * 16 + lg * 4 + r;
            *reinterpret_cast<short*>(Lds + m * 400 + c * 2) =
                f2bs((acc[mr][nr][r] + bias) * qs);
          }
      }
    }
    __builtin_amdgcn_s_barrier();
    const int ncch = nqk >> 3;                     // b128 chunk-cols per row
    const int total = 256 * ncch;
    for (int g = tid; g < total; g += 512) {
      const int m = g / ncch, cc = g - m * ncch;
      const f32x4 v =
          *reinterpret_cast<const f32x4*>(Lds + m * 400 + cc * 16);
      *reinterpret_cast<f32x4*>(
          &QKV[(size_t)(m0 + m) * ND3 + n0 + cc * 8]) = v;
    }
  }
}

// ----------------------------------------------------------- flash attention
// r17 attn verbatim (best measured ~33 us): q-split waves, static-offset
// softmax (SBIAS in a constant C register), raw v_exp_f32, v_perm_b32 pack,
// V read as b128 pairs (kv-permuted Vt), 2K+3V LDS slots (40KB), 4 blocks/CU,
// QK one tile ahead, raw barrier + vmcnt drain, XOR-swizzled staging, LPT.
__global__ __launch_bounds__(256, 4) void attn_kernel(
    const short* __restrict__ QKV, const short* __restrict__ Vtg,
    float* __restrict__ Out) {
  __shared__ short KV[5][4096];   // 40KB: K slots @0,8192; V @16384/24576/32768
  const int tid = threadIdx.x;
  const int lane = tid & 63, wid = tid >> 6;
  const int l15 = lane & 15, lg = lane >> 4;
  const int bh = blockIdx.x;
  const int qt = (S_ / 64 - 1) - (int)blockIdx.y;   // LPT: longest first
  const int b = bh >> 4, h = bh & 15;
  const int q0 = qt * 64;
  const short* Qg = QKV + (size_t)b * S_ * ND3 + h * DH_;
  const short* Kg = QKV + (size_t)b * S_ * ND3 + D_ + h * DH_;
  const short* Vg = Vtg + (size_t)bh * DH_ * S_;

  const int srow = tid >> 3;
  const int scol = ((tid & 7) ^ (srow & 7)) * 8;
  const char* kbase = (const char*)&KV[0][0];
  char* dst = (char*)kbase + (tid & 192) * 16;
  int ka[2];
#pragma unroll
  for (int ks = 0; ks < 2; ++ks)
    ka[ks] = l15 * 128 + ((((ks * 4 + lg)) ^ (l15 & 7)) << 4);
  const int qrow_g = q0 + wid * 16 + l15;

  bf16x8 qf[2];
#pragma unroll
  for (int ks = 0; ks < 2; ++ks)
    qf[ks] = *reinterpret_cast<const bf16x8*>(Qg + (size_t)qrow_g * ND3 +
                                              ks * 32 + lg * 8);

  const f32x4 cinit = (f32x4){SBIAS, SBIAS, SBIAS, SBIAS};  // constant C reg

  f32x4 o[4];
#pragma unroll
  for (int i = 0; i < 4; ++i) o[i] = (f32x4){0.f, 0.f, 0.f, 0.f};
  float lsum = 0.f;

  const short* kp = Kg + (size_t)srow * ND3 + scol;
  const short* vp = Vg + (size_t)srow * S_ + scol;

#define STAGE_AT(KOFF, VOFF)                                                  \
  {                                                                           \
    gl_lds16(kp, dst + (KOFF));                                               \
    gl_lds16(kp + 32 * ND3, dst + (KOFF) + 4096);                             \
    gl_lds16(vp, dst + (VOFF));                                               \
    gl_lds16(vp + 32 * S_, dst + (VOFF) + 4096);                              \
    kp += 64 * ND3;                                                           \
    vp += 64;                                                                 \
  }

  int kr = 8192, kw = 0;
  int vr = 16384, vw = 32768;          // VSUM = 73728

  STAGE_AT(0, 16384);
  if (qt >= 1) STAGE_AT(8192, 24576);
  asm volatile("s_waitcnt vmcnt(0)" ::: "memory");
  __builtin_amdgcn_s_barrier();
  __builtin_amdgcn_sched_barrier(0);

  f32x4 sA[4], sB[4];
#pragma unroll
  for (int nt = 0; nt < 4; ++nt)
    sA[nt] = __builtin_amdgcn_mfma_f32_16x16x32_bf16(
        *reinterpret_cast<const bf16x8*>(kbase + ka[0] + nt * 2048), qf[0],
        cinit, 0, 0, 0);
#pragma unroll
  for (int nt = 0; nt < 4; ++nt)
    sA[nt] = __builtin_amdgcn_mfma_f32_16x16x32_bf16(
        *reinterpret_cast<const bf16x8*>(kbase + ka[1] + nt * 2048), qf[1],
        sA[nt], 0, 0, 0);

#define STEP_BODY(T, SC, SN)                                                  \
  {                                                                           \
    const int T_ = (T);                                                       \
    if (T_ + 2 <= qt) STAGE_AT(kw, vw);                                       \
    if (T_ + 1 <= qt) {                                                       \
      _Pragma("unroll") for (int nt = 0; nt < 4; ++nt)                        \
          SN[nt] = __builtin_amdgcn_mfma_f32_16x16x32_bf16(                   \
              *reinterpret_cast<const bf16x8*>(kbase + kr + ka[0] +           \
                                               nt * 2048),                    \
              qf[0], cinit, 0, 0, 0);                                         \
      _Pragma("unroll") for (int nt = 0; nt < 4; ++nt)                        \
          SN[nt] = __builtin_amdgcn_mfma_f32_16x16x32_bf16(                   \
              *reinterpret_cast<const bf16x8*>(kbase + kr + ka[1] +           \
                                               nt * 2048),                    \
              qf[1], SN[nt], 0, 0, 0);                                        \
    }                                                                         \
    if (T_ == qt) { /* causal mask on diagonal tile */                        \
      const int kv0 = T_ * 64;                                                \
      _Pragma("unroll") for (int nt = 0; nt < 4; ++nt)                        \
        _Pragma("unroll") for (int r = 0; r < 4; ++r)                         \
          if (kv0 + nt * 16 + lg * 4 + r > qrow_g) SC[nt][r] = MASKVAL;       \
    }                                                                         \
    float rowsum = 0.f;                                                       \
    bf16x4 pk[4];                                                             \
    _Pragma("unroll") for (int nt = 0; nt < 4; ++nt) {                        \
      const float p0 = EXP2(SC[nt][0]);                                       \
      const float p1 = EXP2(SC[nt][1]);                                       \
      const float p2 = EXP2(SC[nt][2]);                                       \
      const float p3 = EXP2(SC[nt][3]);                                       \
      rowsum += (p0 + p1) + (p2 + p3);                                        \
      union { uint32_t u[2]; bf16x4 v; } pu;                                  \
      pu.u[0] = __builtin_amdgcn_perm(__float_as_uint(p1),                    \
                                      __float_as_uint(p0), 0x07060302u);      \
      pu.u[1] = __builtin_amdgcn_perm(__float_as_uint(p3),                    \
                                      __float_as_uint(p2), 0x07060302u);      \
      pk[nt] = pu.v;                                                          \
    }                                                                         \
    lsum += rowsum;                                                           \
    _Pragma("unroll") for (int p = 0; p < 2; ++p)                             \
      _Pragma("unroll") for (int ntd = 0; ntd < 4; ++ntd) {                   \
        const bf16x8 vf8 = *reinterpret_cast<const bf16x8*>(                  \
            kbase + vr + ka[p] + ntd * 2048);                                 \
        const bf16x4 vlo = __builtin_shufflevector(vf8, vf8, 0, 1, 2, 3);     \
        const bf16x4 vhi = __builtin_shufflevector(vf8, vf8, 4, 5, 6, 7);     \
        o[ntd] = __builtin_amdgcn_mfma_f32_16x16x16bf16_1k(vlo, pk[2 * p],    \
                                                           o[ntd], 0, 0, 0);  \
        o[ntd] = __builtin_amdgcn_mfma_f32_16x16x16bf16_1k(                   \
            vhi, pk[2 * p + 1], o[ntd], 0, 0, 0);                             \
      }                                                                       \
    if (T_ < qt) {                                                            \
      asm volatile("s_waitcnt vmcnt(0)" ::: "memory");                        \
      __builtin_amdgcn_s_barrier();                                           \
      __builtin_amdgcn_sched_barrier(0);                                      \
    }                                                                         \
    kr ^= 8192; kw ^= 8192;                                                   \
    { const int tv = vr; vr = 73728 - vr - vw; vw = tv; }                     \
  }

  for (int t = 0; t <= qt; t += 2) {
    STEP_BODY(t, sA, sB);
    if (t + 1 <= qt) STEP_BODY(t + 1, sB, sA);
  }
#undef STEP_BODY
#undef STAGE_AT

  float ls = lsum;
  ls += __shfl_xor(ls, 16);
  ls += __shfl_xor(ls, 32);
  const float inv = 1.f / ls;
#pragma unroll
  for (int nt = 0; nt < 4; ++nt) {
    f32x4 v = {o[nt][0] * inv, o[nt][1] * inv, o[nt][2] * inv, o[nt][3] * inv};
    *reinterpret_cast<f32x4*>(
        &Out[((size_t)b * S_ + qrow_g) * D_ + h * DH_ + nt * 16 + lg * 4]) = v;
  }
}

// ---------------------------------------------------------------- launcher
extern "C" void kernel_launch(void* const* d_in, const int* in_sizes, int n_in,
                              void* d_out, int out_size, void* d_ws,
                              size_t ws_size, hipStream_t stream) {
  const float* x  = (const float*)d_in[0];
  const float* Wq = (const float*)d_in[1];
  const float* bq = (const float*)d_in[2];
  const float* Wk = (const float*)d_in[3];
  const float* bk = (const float*)d_in[4];
  const float* Wv = (const float*)d_in[5];
  const float* bv = (const float*)d_in[6];
  float* out = (float*)d_out;

  char* ws = (char*)d_ws;
  short* xb  = (short*)(ws);             //  8 MB: [4096][1024] bf16
  short* Wt  = (short*)(ws + 8388608);   //  6 MB: [3072][1024] bf16
  short* qkv = (short*)(ws + 14680064);  // 24 MB: [4096][3072] bf16 (V unused)
  short* Vt  = (short*)(ws + 39845888);  //  8 MB: [32][64][2048] bf16 (kv-permuted)

  prep_kernel<<<dim3(4096 + 3072), dim3(256), 0, stream>>>(x, Wq, Wk, Wv, xb,
                                                           Wt);
  qkv_gemm_kernel<<<dim3(256), dim3(512), 0, stream>>>(xb, Wt, bq, bk, bv,
                                                       qkv, Vt);
  attn_kernel<<<dim3(B_ * H_, S_ / 64), dim3(256), 0, stream>>>(qkv, Vt, out);
}

// Round 21
// 67.740 us; speedup vs baseline: 1.0925x; 1.0177x over previous
//
#include <hip/hip_runtime.h>
#include <hip/hip_bf16.h>
#include <stdint.h>

// Problem constants
#define B_    2
#define S_    2048
#define H_    16
#define DH_   64
#define D_    1024
#define ND3   3072      // 3*D
#define MTOT  4096      // B*S
#define L2E   1.4426950408889634f
#define MASKVAL (-3.0e38f)   // causal mask: exp2(MASKVAL) == 0
#define SBIAS   (-14.0f)     // static softmax offset (log2 units)

typedef __attribute__((ext_vector_type(8))) short bf16x8;
typedef __attribute__((ext_vector_type(4))) short bf16x4;
typedef __attribute__((ext_vector_type(4))) float f32x4;

// raw v_exp_f32 (no OCML denormal fixup; exact for normal range, and
// exp2(-3e38) == 0 as required by the mask path)
#if __has_builtin(__builtin_amdgcn_exp2f)
#define EXP2(x) __builtin_amdgcn_exp2f(x)
#else
#define EXP2(x) exp2f(x)
#endif

__device__ inline short f2bs(float f) {
  __hip_bfloat16 h = __float2bfloat16(f);
  return *reinterpret_cast<short*>(&h);
}

__device__ inline void gl_lds16(const void* g, void* l) {
  __builtin_amdgcn_global_load_lds(
      (const __attribute__((address_space(1))) uint32_t*)g,
      (__attribute__((address_space(3))) uint32_t*)l, 16, 0, 0);
}

// --------------------------------------- fused prep: x->bf16 and W->Wt bf16
__global__ __launch_bounds__(256) void prep_kernel(
    const float* __restrict__ X, const float* __restrict__ Wq,
    const float* __restrict__ Wk, const float* __restrict__ Wv,
    short* __restrict__ Xb, short* __restrict__ Wt) {
  __shared__ float t[32][33];
  int bid = blockIdx.x;
  if (bid < 4096) {
    const int i = (bid * 256 + threadIdx.x) * 4;
    float4 v = *reinterpret_cast<const float4*>(X + i);
    bf16x4 o;
    o[0] = f2bs(v.x); o[1] = f2bs(v.y); o[2] = f2bs(v.z); o[3] = f2bs(v.w);
    *reinterpret_cast<bf16x4*>(Xb + i) = o;
  } else {
    bid -= 4096;
    const int z = bid >> 10;             // 0..2 : Wq/Wk/Wv
    const int rem = bid & 1023;
    const int n0 = (rem & 31) * 32, k0 = (rem >> 5) * 32;
    const int x = threadIdx.x & 31, y = threadIdx.x >> 5;   // y in 0..7
    const float* W = z == 0 ? Wq : (z == 1 ? Wk : Wv);
    short* out = Wt + (size_t)z * (D_ * D_);
#pragma unroll
    for (int i = 0; i < 4; ++i)
      t[y + 8 * i][x] = W[(size_t)(k0 + y + 8 * i) * D_ + n0 + x];
    __syncthreads();
#pragma unroll
    for (int i = 0; i < 4; ++i)
      out[(size_t)(n0 + y + 8 * i) * D_ + k0 + x] = f2bs(t[x][y + 8 * i]);
  }
}

// ------------------------------------------------- QKV GEMM, 128x192 8-phase
// r21: BM 256->128 so grid = 32x16 = 512 blocks = 2 blocks/CU (LDS 80KB x 2
// = 160KB exactly) — restores cross-block implicit overlap (one block's MFMA
// covers the other's barrier/drain stalls; the 1-block/CU r20 config had
// none). Same proven structure: all 5 staged pieces at P0/P1, single
// vmcnt(0) drain at P3-end, XOR swizzle both sides, LDS-bounce Q/K epilogue,
// kv-permuted V epilogue for attn b128 pair reads.
__global__ __launch_bounds__(512, 2) void qkv_gemm_kernel(
    const short* __restrict__ Xb, const short* __restrict__ Wt,
    const float* __restrict__ bq, const float* __restrict__ bk,
    const float* __restrict__ bv, short* __restrict__ QKV,
    short* __restrict__ Vt) {
  __shared__ char Lds[81920];   // buf d @ d*40960: A 16KB @+0, B 24KB @+16384
  const int tid = threadIdx.x;
  const int lane = tid & 63;
  const int wid = tid >> 6;
  const int l15 = lane & 15, lg = lane >> 4;
  const int wm = wid >> 2, wn = wid & 3;         // wave tile 64x48
  const int bid = blockIdx.x;
  const int wgid = (bid & 7) * 64 + (bid >> 3);  // XCD swizzle (512%8==0)
  const int m0 = (wgid >> 4) * 128, n0 = (wgid & 15) * 192;

  const int srow = tid >> 3;                         // 0..63
  const int scol = ((tid & 7) ^ (srow & 7)) * 8;
  const short* pa = Xb + (size_t)(m0 + srow) * D_ + scol;
  const short* pb = Wt + (size_t)(n0 + srow) * D_ + scol;
  char* sdst = Lds + (tid & 448) * 16;               // wave-uniform base

  const int abase = wm * 8192;                       // A rows wm*64..+63
  int a_off[4][2], b_off[3][2];
#pragma unroll
  for (int mr = 0; mr < 4; ++mr)
#pragma unroll
    for (int ks = 0; ks < 2; ++ks)
      a_off[mr][ks] =
          (mr * 16 + l15) * 128 + ((((ks * 4 + lg)) ^ (l15 & 7)) << 4);
#pragma unroll
  for (int nr = 0; nr < 3; ++nr)
#pragma unroll
    for (int ks = 0; ks < 2; ++ks)
      b_off[nr][ks] = (wn * 48 + nr * 16 + l15) * 128 +
                      ((((ks * 4 + lg)) ^ (l15 & 7)) << 4);

  f32x4 acc[4][3];
#pragma unroll
  for (int i = 0; i < 4; ++i)
#pragma unroll
    for (int j = 0; j < 3; ++j) acc[i][j] = (f32x4){0.f, 0.f, 0.f, 0.f};

#define BARRIER()                                                             \
  __builtin_amdgcn_s_barrier();                                               \
  __builtin_amdgcn_sched_barrier(0)

  // prologue: stage tile 0 fully into buf0 (2 A pieces + 3 B pieces)
  gl_lds16(pa, sdst);
  gl_lds16(pa + (size_t)64 * D_, sdst + 8192);
  gl_lds16(pb, sdst + 16384);
  gl_lds16(pb + (size_t)64 * D_, sdst + 24576);
  gl_lds16(pb + (size_t)128 * D_, sdst + 32768);
  asm volatile("s_waitcnt vmcnt(0)" ::: "memory");
  BARRIER();

#define TILE(J, DL)                                                           \
  {                                                                           \
    const int j_ = (J);                                                       \
    const bool stg = (j_ + 1 < 16);                                           \
    const int RD = (DL) * 40960;                                              \
    const int WD = (1 - (DL)) * 40960;                                        \
    const short* pa1 = pa + (j_ + 1) * 64;                                    \
    const short* pb1 = pb + (j_ + 1) * 64;                                    \
    bf16x8 af[2], bf0, bf1, bf2;                                              \
    /* P0: stage A-lo,A-hi,B0; frags B ks0 + A ks0 mr0-1; MFMA acc[0..1] */   \
    if (stg) {                                                                \
      gl_lds16(pa1, sdst + WD);                                               \
      gl_lds16(pa1 + (size_t)64 * D_, sdst + WD + 8192);                      \
      gl_lds16(pb1, sdst + WD + 16384);                                       \
    }                                                                         \
    bf0 = *reinterpret_cast<const bf16x8*>(Lds + RD + 16384 + b_off[0][0]);   \
    bf1 = *reinterpret_cast<const bf16x8*>(Lds + RD + 16384 + b_off[1][0]);   \
    bf2 = *reinterpret_cast<const bf16x8*>(Lds + RD + 16384 + b_off[2][0]);   \
    _Pragma("unroll") for (int mr = 0; mr < 2; ++mr) af[mr] =                 \
        *reinterpret_cast<const bf16x8*>(Lds + RD + abase + a_off[mr][0]);    \
    BARRIER();                                                                \
    __builtin_amdgcn_s_setprio(1);                                            \
    _Pragma("unroll") for (int mr = 0; mr < 2; ++mr) {                        \
      acc[mr][0] = __builtin_amdgcn_mfma_f32_16x16x32_bf16(af[mr], bf0,       \
                                                           acc[mr][0], 0, 0,  \
                                                           0);                \
      acc[mr][1] = __builtin_amdgcn_mfma_f32_16x16x32_bf16(af[mr], bf1,       \
                                                           acc[mr][1], 0, 0,  \
                                                           0);                \
      acc[mr][2] = __builtin_amdgcn_mfma_f32_16x16x32_bf16(af[mr], bf2,       \
                                                           acc[mr][2], 0, 0,  \
                                                           0);                \
    }                                                                         \
    __builtin_amdgcn_s_setprio(0);                                            \
    BARRIER();                                                                \
    /* P1: stage B1,B2; frags A ks0 mr2-3; MFMA acc[2..3] */                  \
    if (stg) {                                                                \
      gl_lds16(pb1 + (size_t)64 * D_, sdst + WD + 24576);                     \
      gl_lds16(pb1 + (size_t)128 * D_, sdst + WD + 32768);                    \
    }                                                                         \
    _Pragma("unroll") for (int mr = 0; mr < 2; ++mr) af[mr] =                 \
        *reinterpret_cast<const bf16x8*>(Lds + RD + abase +                   \
                                         a_off[mr + 2][0]);                   \
    BARRIER();                                                                \
    __builtin_amdgcn_s_setprio(1);                                            \
    _Pragma("unroll") for (int mr = 0; mr < 2; ++mr) {                        \
      acc[mr + 2][0] = __builtin_amdgcn_mfma_f32_16x16x32_bf16(               \
          af[mr], bf0, acc[mr + 2][0], 0, 0, 0);                              \
      acc[mr + 2][1] = __builtin_amdgcn_mfma_f32_16x16x32_bf16(               \
          af[mr], bf1, acc[mr + 2][1], 0, 0, 0);                              \
      acc[mr + 2][2] = __builtin_amdgcn_mfma_f32_16x16x32_bf16(               \
          af[mr], bf2, acc[mr + 2][2], 0, 0, 0);                              \
    }                                                                         \
    __builtin_amdgcn_s_setprio(0);                                            \
    BARRIER();                                                                \
    /* P2: frags B ks1 + A ks1 mr0-1; MFMA acc[0..1] */                       \
    bf0 = *reinterpret_cast<const bf16x8*>(Lds + RD + 16384 + b_off[0][1]);   \
    bf1 = *reinterpret_cast<const bf16x8*>(Lds + RD + 16384 + b_off[1][1]);   \
    bf2 = *reinterpret_cast<const bf16x8*>(Lds + RD + 16384 + b_off[2][1]);   \
    _Pragma("unroll") for (int mr = 0; mr < 2; ++mr) af[mr] =                 \
        *reinterpret_cast<const bf16x8*>(Lds + RD + abase + a_off[mr][1]);    \
    BARRIER();                                                                \
    __builtin_amdgcn_s_setprio(1);                                            \
    _Pragma("unroll") for (int mr = 0; mr < 2; ++mr) {                        \
      acc[mr][0] = __builtin_amdgcn_mfma_f32_16x16x32_bf16(af[mr], bf0,       \
                                                           acc[mr][0], 0, 0,  \
                                                           0);                \
      acc[mr][1] = __builtin_amdgcn_mfma_f32_16x16x32_bf16(af[mr], bf1,       \
                                                           acc[mr][1], 0, 0,  \
                                                           0);                \
      acc[mr][2] = __builtin_amdgcn_mfma_f32_16x16x32_bf16(af[mr], bf2,       \
                                                           acc[mr][2], 0, 0,  \
                                                           0);                \
    }                                                                         \
    __builtin_amdgcn_s_setprio(0);                                            \
    BARRIER();                                                                \
    /* P3: frags A ks1 mr2-3; MFMA acc[2..3]; drain staged loads */           \
    _Pragma("unroll") for (int mr = 0; mr < 2; ++mr) af[mr] =                 \
        *reinterpret_cast<const bf16x8*>(Lds + RD + abase +                   \
                                         a_off[mr + 2][1]);                   \
    BARRIER();                                                                \
    __builtin_amdgcn_s_setprio(1);                                            \
    _Pragma("unroll") for (int mr = 0; mr < 2; ++mr) {                        \
      acc[mr + 2][0] = __builtin_amdgcn_mfma_f32_16x16x32_bf16(               \
          af[mr], bf0, acc[mr + 2][0], 0, 0, 0);                              \
      acc[mr + 2][1] = __builtin_amdgcn_mfma_f32_16x16x32_bf16(               \
          af[mr], bf1, acc[mr + 2][1], 0, 0, 0);                              \
      acc[mr + 2][2] = __builtin_amdgcn_mfma_f32_16x16x32_bf16(               \
          af[mr], bf2, acc[mr + 2][2], 0, 0, 0);                              \
    }                                                                         \
    __builtin_amdgcn_s_setprio(0);                                            \
    asm volatile("s_waitcnt vmcnt(0)" ::: "memory");                          \
    BARRIER();                                                                \
  }

  for (int jj = 0; jj < 16; jj += 2) {
    TILE(jj, 0);
    TILE(jj + 1, 1);
  }
#undef TILE
#undef BARRIER

  // ---- epilogue ----
  const int wr = wm * 64;
  const int nqk = (n0 >= 2 * D_) ? 0
                  : ((2 * D_ - n0 < 192) ? (2 * D_ - n0) : 192);

  // V columns: per-lane kv-permuted b64 stores
#pragma unroll
  for (int nr = 0; nr < 3; ++nr) {
    const int c = wn * 48 + nr * 16 + l15;         // local col
    if (c >= nqk) {
      const int f = n0 + c - 2 * D_;               // v-feature 0..1023
      const float bias = bv[f];
      const int base0 = (m0 & 2047) + wr;          // multiple of 64
      short* vout = Vt + ((size_t)((m0 >> 11) * H_ + (f >> 6)) * DH_ +
                          (f & 63)) * S_;
#pragma unroll
      for (int mr = 0; mr < 4; ++mr) {             // rows mr*16+lg*4+r of 64
        bf16x4 pv;
#pragma unroll
        for (int r = 0; r < 4; ++r) pv[r] = f2bs(acc[mr][nr][r] + bias);
        const int s_new = base0 + ((mr >> 1) * 4 + lg) * 8 + (mr & 1) * 4;
        *reinterpret_cast<bf16x4*>(vout + s_new) = pv;
      }
    }
  }

  // Q/K columns: LDS-bounce for coalesced b128 stores (LDS dead after loop;
  // tile 128 rows x 400B stride = 51.2KB < 80KB).
  if (nqk > 0) {
#pragma unroll
    for (int nr = 0; nr < 3; ++nr) {
      const int c = wn * 48 + nr * 16 + l15;
      if (c < nqk) {                               // wave-uniform (x16 bounds)
        const int col = n0 + c;
        float bias, qs;
        if (col < D_) { bias = bq[col];      qs = 0.125f * L2E; }
        else          { bias = bk[col - D_]; qs = 1.f; }
#pragma unroll
        for (int mr = 0; mr < 4; ++mr)
#pragma unroll
          for (int r = 0; r < 4; ++r) {
            const int m = wr + mr * 16 + lg * 4 + r;
            *reinterpret_cast<short*>(Lds + m * 400 + c * 2) =
                f2bs((acc[mr][nr][r] + bias) * qs);
          }
      }
    }
    __builtin_amdgcn_s_barrier();
    const int ncch = nqk >> 3;                     // b128 chunk-cols per row
    const int total = 128 * ncch;
    for (int g = tid; g < total; g += 512) {
      const int m = g / ncch, cc = g - m * ncch;
      const f32x4 v =
          *reinterpret_cast<const f32x4*>(Lds + m * 400 + cc * 16);
      *reinterpret_cast<f32x4*>(
          &QKV[(size_t)(m0 + m) * ND3 + n0 + cc * 8]) = v;
    }
  }
}

// ----------------------------------------------------------- flash attention
// r17 attn verbatim (best measured ~33 us): q-split waves, static-offset
// softmax (SBIAS in a constant C register), raw v_exp_f32, v_perm_b32 pack,
// V read as b128 pairs (kv-permuted Vt), 2K+3V LDS slots (40KB), 4 blocks/CU,
// QK one tile ahead, raw barrier + vmcnt drain, XOR-swizzled staging, LPT.
__global__ __launch_bounds__(256, 4) void attn_kernel(
    const short* __restrict__ QKV, const short* __restrict__ Vtg,
    float* __restrict__ Out) {
  __shared__ short KV[5][4096];   // 40KB: K slots @0,8192; V @16384/24576/32768
  const int tid = threadIdx.x;
  const int lane = tid & 63, wid = tid >> 6;
  const int l15 = lane & 15, lg = lane >> 4;
  const int bh = blockIdx.x;
  const int qt = (S_ / 64 - 1) - (int)blockIdx.y;   // LPT: longest first
  const int b = bh >> 4, h = bh & 15;
  const int q0 = qt * 64;
  const short* Qg = QKV + (size_t)b * S_ * ND3 + h * DH_;
  const short* Kg = QKV + (size_t)b * S_ * ND3 + D_ + h * DH_;
  const short* Vg = Vtg + (size_t)bh * DH_ * S_;

  const int srow = tid >> 3;
  const int scol = ((tid & 7) ^ (srow & 7)) * 8;
  const char* kbase = (const char*)&KV[0][0];
  char* dst = (char*)kbase + (tid & 192) * 16;
  int ka[2];
#pragma unroll
  for (int ks = 0; ks < 2; ++ks)
    ka[ks] = l15 * 128 + ((((ks * 4 + lg)) ^ (l15 & 7)) << 4);
  const int qrow_g = q0 + wid * 16 + l15;

  bf16x8 qf[2];
#pragma unroll
  for (int ks = 0; ks < 2; ++ks)
    qf[ks] = *reinterpret_cast<const bf16x8*>(Qg + (size_t)qrow_g * ND3 +
                                              ks * 32 + lg * 8);

  const f32x4 cinit = (f32x4){SBIAS, SBIAS, SBIAS, SBIAS};  // constant C reg

  f32x4 o[4];
#pragma unroll
  for (int i = 0; i < 4; ++i) o[i] = (f32x4){0.f, 0.f, 0.f, 0.f};
  float lsum = 0.f;

  const short* kp = Kg + (size_t)srow * ND3 + scol;
  const short* vp = Vg + (size_t)srow * S_ + scol;

#define STAGE_AT(KOFF, VOFF)                                                  \
  {                                                                           \
    gl_lds16(kp, dst + (KOFF));                                               \
    gl_lds16(kp + 32 * ND3, dst + (KOFF) + 4096);                             \
    gl_lds16(vp, dst + (VOFF));                                               \
    gl_lds16(vp + 32 * S_, dst + (VOFF) + 4096);                              \
    kp += 64 * ND3;                                                           \
    vp += 64;                                                                 \
  }

  int kr = 8192, kw = 0;
  int vr = 16384, vw = 32768;          // VSUM = 73728

  STAGE_AT(0, 16384);
  if (qt >= 1) STAGE_AT(8192, 24576);
  asm volatile("s_waitcnt vmcnt(0)" ::: "memory");
  __builtin_amdgcn_s_barrier();
  __builtin_amdgcn_sched_barrier(0);

  f32x4 sA[4], sB[4];
#pragma unroll
  for (int nt = 0; nt < 4; ++nt)
    sA[nt] = __builtin_amdgcn_mfma_f32_16x16x32_bf16(
        *reinterpret_cast<const bf16x8*>(kbase + ka[0] + nt * 2048), qf[0],
        cinit, 0, 0, 0);
#pragma unroll
  for (int nt = 0; nt < 4; ++nt)
    sA[nt] = __builtin_amdgcn_mfma_f32_16x16x32_bf16(
        *reinterpret_cast<const bf16x8*>(kbase + ka[1] + nt * 2048), qf[1],
        sA[nt], 0, 0, 0);

#define STEP_BODY(T, SC, SN)                                                  \
  {                                                                           \
    const int T_ = (T);                                                       \
    if (T_ + 2 <= qt) STAGE_AT(kw, vw);                                       \
    if (T_ + 1 <= qt) {                                                       \
      _Pragma("unroll") for (int nt = 0; nt < 4; ++nt)                        \
          SN[nt] = __builtin_amdgcn_mfma_f32_16x16x32_bf16(                   \
              *reinterpret_cast<const bf16x8*>(kbase + kr + ka[0] +           \
                                               nt * 2048),                    \
              qf[0], cinit, 0, 0, 0);                                         \
      _Pragma("unroll") for (int nt = 0; nt < 4; ++nt)                        \
          SN[nt] = __builtin_amdgcn_mfma_f32_16x16x32_bf16(                   \
              *reinterpret_cast<const bf16x8*>(kbase + kr + ka[1] +           \
                                               nt * 2048),                    \
              qf[1], SN[nt], 0, 0, 0);                                        \
    }                                                                         \
    if (T_ == qt) { /* causal mask on diagonal tile */                        \
      const int kv0 = T_ * 64;                                                \
      _Pragma("unroll") for (int nt = 0; nt < 4; ++nt)                        \
        _Pragma("unroll") for (int r = 0; r < 4; ++r)                         \
          if (kv0 + nt * 16 + lg * 4 + r > qrow_g) SC[nt][r] = MASKVAL;       \
    }                                                                         \
    float rowsum = 0.f;                                                       \
    bf16x4 pk[4];                                                             \
    _Pragma("unroll") for (int nt = 0; nt < 4; ++nt) {                        \
      const float p0 = EXP2(SC[nt][0]);                                       \
      const float p1 = EXP2(SC[nt][1]);                                       \
      const float p2 = EXP2(SC[nt][2]);                                       \
      const float p3 = EXP2(SC[nt][3]);                                       \
      rowsum += (p0 + p1) + (p2 + p3);                                        \
      union { uint32_t u[2]; bf16x4 v; } pu;                                  \
      pu.u[0] = __builtin_amdgcn_perm(__float_as_uint(p1),                    \
                                      __float_as_uint(p0), 0x07060302u);      \
      pu.u[1] = __builtin_amdgcn_perm(__float_as_uint(p3),                    \
                                      __float_as_uint(p2), 0x07060302u);      \
      pk[nt] = pu.v;                                                          \
    }                                                                         \
    lsum += rowsum;                                                           \
    _Pragma("unroll") for (int p = 0; p < 2; ++p)                             \
      _Pragma("unroll") for (int ntd = 0; ntd < 4; ++ntd) {                   \
        const bf16x8 vf8 = *reinterpret_cast<const bf16x8*>(                  \
            kbase + vr + ka[p] + ntd * 2048);                                 \
        const bf16x4 vlo = __builtin_shufflevector(vf8, vf8, 0, 1, 2, 3);     \
        const bf16x4 vhi = __builtin_shufflevector(vf8, vf8, 4, 5, 6, 7);     \
        o[ntd] = __builtin_amdgcn_mfma_f32_16x16x16bf16_1k(vlo, pk[2 * p],    \
                                                           o[ntd], 0, 0, 0);  \
        o[ntd] = __builtin_amdgcn_mfma_f32_16x16x16bf16_1k(                   \
            vhi, pk[2 * p + 1], o[ntd], 0, 0, 0);                             \
      }                                                                       \
    if (T_ < qt) {                                                            \
      asm volatile("s_waitcnt vmcnt(0)" ::: "memory");                        \
      __builtin_amdgcn_s_barrier();                                           \
      __builtin_amdgcn_sched_barrier(0);                                      \
    }                                                                         \
    kr ^= 8192; kw ^= 8192;                                                   \
    { const int tv = vr; vr = 73728 - vr - vw; vw = tv; }                     \
  }

  for (int t = 0; t <= qt; t += 2) {
    STEP_BODY(t, sA, sB);
    if (t + 1 <= qt) STEP_BODY(t + 1, sB, sA);
  }
#undef STEP_BODY
#undef STAGE_AT

  float ls = lsum;
  ls += __shfl_xor(ls, 16);
  ls += __shfl_xor(ls, 32);
  const float inv = 1.f / ls;
#pragma unroll
  for (int nt = 0; nt < 4; ++nt) {
    f32x4 v = {o[nt][0] * inv, o[nt][1] * inv, o[nt][2] * inv, o[nt][3] * inv};
    *reinterpret_cast<f32x4*>(
        &Out[((size_t)b * S_ + qrow_g) * D_ + h * DH_ + nt * 16 + lg * 4]) = v;
  }
}

// ---------------------------------------------------------------- launcher
extern "C" void kernel_launch(void* const* d_in, const int* in_sizes, int n_in,
                              void* d_out, int out_size, void* d_ws,
                              size_t ws_size, hipStream_t stream) {
  const float* x  = (const float*)d_in[0];
  const float* Wq = (const float*)d_in[1];
  const float* bq = (const float*)d_in[2];
  const float* Wk = (const float*)d_in[3];
  const float* bk = (const float*)d_in[4];
  const float* Wv = (const float*)d_in[5];
  const float* bv = (const float*)d_in[6];
  float* out = (float*)d_out;

  char* ws = (char*)d_ws;
  short* xb  = (short*)(ws);             //  8 MB: [4096][1024] bf16
  short* Wt  = (short*)(ws + 8388608);   //  6 MB: [3072][1024] bf16
  short* qkv = (short*)(ws + 14680064);  // 24 MB: [4096][3072] bf16 (V unused)
  short* Vt  = (short*)(ws + 39845888);  //  8 MB: [32][64][2048] bf16 (kv-permuted)

  prep_kernel<<<dim3(4096 + 3072), dim3(256), 0, stream>>>(x, Wq, Wk, Wv, xb,
                                                           Wt);
  qkv_gemm_kernel<<<dim3(512), dim3(512), 0, stream>>>(xb, Wt, bq, bk, bv,
                                                       qkv, Vt);
  attn_kernel<<<dim3(B_ * H_, S_ / 64), dim3(256), 0, stream>>>(qkv, Vt, out);
}

// Round 22
// 67.102 us; speedup vs baseline: 1.1029x; 1.0095x over previous
//
#include <hip/hip_runtime.h>
#include <hip/hip_bf16.h>
#include <stdint.h>

// Problem constants
#define B_    2
#define S_    2048
#define H_    16
#define DH_   64
#define D_    1024
#define ND3   3072      // 3*D
#define MTOT  4096      // B*S
#define L2E   1.4426950408889634f
#define MASKVAL (-3.0e38f)   // causal mask: exp2(MASKVAL) == 0
#define SBIAS   (-14.0f)     // static softmax offset (log2 units)

typedef __attribute__((ext_vector_type(8))) short bf16x8;
typedef __attribute__((ext_vector_type(4))) short bf16x4;
typedef __attribute__((ext_vector_type(4))) float f32x4;

// raw v_exp_f32 (no OCML denormal fixup; exact for normal range, and
// exp2(-3e38) == 0 as required by the mask path)
#if __has_builtin(__builtin_amdgcn_exp2f)
#define EXP2(x) __builtin_amdgcn_exp2f(x)
#else
#define EXP2(x) exp2f(x)
#endif

__device__ inline short f2bs(float f) {
  __hip_bfloat16 h = __float2bfloat16(f);
  return *reinterpret_cast<short*>(&h);
}

__device__ inline void gl_lds16(const void* g, void* l) {
  __builtin_amdgcn_global_load_lds(
      (const __attribute__((address_space(1))) uint32_t*)g,
      (__attribute__((address_space(3))) uint32_t*)l, 16, 0, 0);
}

// --------------------------------------- fused prep: x->bf16 and W->Wt bf16
__global__ __launch_bounds__(256) void prep_kernel(
    const float* __restrict__ X, const float* __restrict__ Wq,
    const float* __restrict__ Wk, const float* __restrict__ Wv,
    short* __restrict__ Xb, short* __restrict__ Wt) {
  __shared__ float t[32][33];
  int bid = blockIdx.x;
  if (bid < 4096) {
    const int i = (bid * 256 + threadIdx.x) * 4;
    float4 v = *reinterpret_cast<const float4*>(X + i);
    bf16x4 o;
    o[0] = f2bs(v.x); o[1] = f2bs(v.y); o[2] = f2bs(v.z); o[3] = f2bs(v.w);
    *reinterpret_cast<bf16x4*>(Xb + i) = o;
  } else {
    bid -= 4096;
    const int z = bid >> 10;             // 0..2 : Wq/Wk/Wv
    const int rem = bid & 1023;
    const int n0 = (rem & 31) * 32, k0 = (rem >> 5) * 32;
    const int x = threadIdx.x & 31, y = threadIdx.x >> 5;   // y in 0..7
    const float* W = z == 0 ? Wq : (z == 1 ? Wk : Wv);
    short* out = Wt + (size_t)z * (D_ * D_);
#pragma unroll
    for (int i = 0; i < 4; ++i)
      t[y + 8 * i][x] = W[(size_t)(k0 + y + 8 * i) * D_ + n0 + x];
    __syncthreads();
#pragma unroll
    for (int i = 0; i < 4; ++i)
      out[(size_t)(n0 + y + 8 * i) * D_ + k0 + x] = f2bs(t[x][y + 8 * i]);
  }
}

// ------------------------------------------------- QKV GEMM, 128x192 8-phase
// r22: XCD SQUARE swizzle — each XCD owns an 8m x 8n square of the 32x16
// grid so its L2 working set is 2MB (A) + 3MB (B half) = 5MB instead of
// 1MB + ALL of B (7MB > 4MB L2, which streamed 6MB of B from HBM per XCD).
// Everything else identical to r21: 512 blocks = 2/CU, 5 staged pieces at
// P0/P1, single vmcnt(0) drain at P3-end, XOR swizzle both sides,
// LDS-bounce Q/K epilogue, kv-permuted V epilogue.
__global__ __launch_bounds__(512, 2) void qkv_gemm_kernel(
    const short* __restrict__ Xb, const short* __restrict__ Wt,
    const float* __restrict__ bq, const float* __restrict__ bk,
    const float* __restrict__ bv, short* __restrict__ QKV,
    short* __restrict__ Vt) {
  __shared__ char Lds[81920];   // buf d @ d*40960: A 16KB @+0, B 24KB @+16384
  const int tid = threadIdx.x;
  const int lane = tid & 63;
  const int wid = tid >> 6;
  const int l15 = lane & 15, lg = lane >> 4;
  const int wm = wid >> 2, wn = wid & 3;         // wave tile 64x48
  // XCD square swizzle: xcd -> 8m x 8n square (bijective over 32x16)
  const int bid = blockIdx.x;
  const int xcd = bid & 7, idx = bid >> 3;       // idx 0..63
  const int mstrip = (xcd >> 1) * 8 + (idx >> 3);
  const int nstrip = (xcd & 1) * 8 + (idx & 7);
  const int m0 = mstrip * 128, n0 = nstrip * 192;

  const int srow = tid >> 3;                         // 0..63
  const int scol = ((tid & 7) ^ (srow & 7)) * 8;
  const short* pa = Xb + (size_t)(m0 + srow) * D_ + scol;
  const short* pb = Wt + (size_t)(n0 + srow) * D_ + scol;
  char* sdst = Lds + (tid & 448) * 16;               // wave-uniform base

  const int abase = wm * 8192;                       // A rows wm*64..+63
  int a_off[4][2], b_off[3][2];
#pragma unroll
  for (int mr = 0; mr < 4; ++mr)
#pragma unroll
    for (int ks = 0; ks < 2; ++ks)
      a_off[mr][ks] =
          (mr * 16 + l15) * 128 + ((((ks * 4 + lg)) ^ (l15 & 7)) << 4);
#pragma unroll
  for (int nr = 0; nr < 3; ++nr)
#pragma unroll
    for (int ks = 0; ks < 2; ++ks)
      b_off[nr][ks] = (wn * 48 + nr * 16 + l15) * 128 +
                      ((((ks * 4 + lg)) ^ (l15 & 7)) << 4);

  f32x4 acc[4][3];
#pragma unroll
  for (int i = 0; i < 4; ++i)
#pragma unroll
    for (int j = 0; j < 3; ++j) acc[i][j] = (f32x4){0.f, 0.f, 0.f, 0.f};

#define BARRIER()                                                             \
  __builtin_amdgcn_s_barrier();                                               \
  __builtin_amdgcn_sched_barrier(0)

  // prologue: stage tile 0 fully into buf0 (2 A pieces + 3 B pieces)
  gl_lds16(pa, sdst);
  gl_lds16(pa + (size_t)64 * D_, sdst + 8192);
  gl_lds16(pb, sdst + 16384);
  gl_lds16(pb + (size_t)64 * D_, sdst + 24576);
  gl_lds16(pb + (size_t)128 * D_, sdst + 32768);
  asm volatile("s_waitcnt vmcnt(0)" ::: "memory");
  BARRIER();

#define TILE(J, DL)                                                           \
  {                                                                           \
    const int j_ = (J);                                                       \
    const bool stg = (j_ + 1 < 16);                                           \
    const int RD = (DL) * 40960;                                              \
    const int WD = (1 - (DL)) * 40960;                                        \
    const short* pa1 = pa + (j_ + 1) * 64;                                    \
    const short* pb1 = pb + (j_ + 1) * 64;                                    \
    bf16x8 af[2], bf0, bf1, bf2;                                              \
    /* P0: stage A-lo,A-hi,B0; frags B ks0 + A ks0 mr0-1; MFMA acc[0..1] */   \
    if (stg) {                                                                \
      gl_lds16(pa1, sdst + WD);                                               \
      gl_lds16(pa1 + (size_t)64 * D_, sdst + WD + 8192);                      \
      gl_lds16(pb1, sdst + WD + 16384);                                       \
    }                                                                         \
    bf0 = *reinterpret_cast<const bf16x8*>(Lds + RD + 16384 + b_off[0][0]);   \
    bf1 = *reinterpret_cast<const bf16x8*>(Lds + RD + 16384 + b_off[1][0]);   \
    bf2 = *reinterpret_cast<const bf16x8*>(Lds + RD + 16384 + b_off[2][0]);   \
    _Pragma("unroll") for (int mr = 0; mr < 2; ++mr) af[mr] =                 \
        *reinterpret_cast<const bf16x8*>(Lds + RD + abase + a_off[mr][0]);    \
    BARRIER();                                                                \
    __builtin_amdgcn_s_setprio(1);                                            \
    _Pragma("unroll") for (int mr = 0; mr < 2; ++mr) {                        \
      acc[mr][0] = __builtin_amdgcn_mfma_f32_16x16x32_bf16(af[mr], bf0,       \
                                                           acc[mr][0], 0, 0,  \
                                                           0);                \
      acc[mr][1] = __builtin_amdgcn_mfma_f32_16x16x32_bf16(af[mr], bf1,       \
                                                           acc[mr][1], 0, 0,  \
                                                           0);                \
      acc[mr][2] = __builtin_amdgcn_mfma_f32_16x16x32_bf16(af[mr], bf2,       \
                                                           acc[mr][2], 0, 0,  \
                                                           0);                \
    }                                                                         \
    __builtin_amdgcn_s_setprio(0);                                            \
    BARRIER();                                                                \
    /* P1: stage B1,B2; frags A ks0 mr2-3; MFMA acc[2..3] */                  \
    if (stg) {                                                                \
      gl_lds16(pb1 + (size_t)64 * D_, sdst + WD + 24576);                     \
      gl_lds16(pb1 + (size_t)128 * D_, sdst + WD + 32768);                    \
    }                                                                         \
    _Pragma("unroll") for (int mr = 0; mr < 2; ++mr) af[mr] =                 \
        *reinterpret_cast<const bf16x8*>(Lds + RD + abase +                   \
                                         a_off[mr + 2][0]);                   \
    BARRIER();                                                                \
    __builtin_amdgcn_s_setprio(1);                                            \
    _Pragma("unroll") for (int mr = 0; mr < 2; ++mr) {                        \
      acc[mr + 2][0] = __builtin_amdgcn_mfma_f32_16x16x32_bf16(               \
          af[mr], bf0, acc[mr + 2][0], 0, 0, 0);                              \
      acc[mr + 2][1] = __builtin_amdgcn_mfma_f32_16x16x32_bf16(               \
          af[mr], bf1, acc[mr + 2][1], 0, 0, 0);                              \
      acc[mr + 2][2] = __builtin_amdgcn_mfma_f32_16x16x32_bf16(               \
          af[mr], bf2, acc[mr + 2][2], 0, 0, 0);                              \
    }                                                                         \
    __builtin_amdgcn_s_setprio(0);                                            \
    BARRIER();                                                                \
    /* P2: frags B ks1 + A ks1 mr0-1; MFMA acc[0..1] */                       \
    bf0 = *reinterpret_cast<const bf16x8*>(Lds + RD + 16384 + b_off[0][1]);   \
    bf1 = *reinterpret_cast<const bf16x8*>(Lds + RD + 16384 + b_off[1][1]);   \
    bf2 = *reinterpret_cast<const bf16x8*>(Lds + RD + 16384 + b_off[2][1]);   \
    _Pragma("unroll") for (int mr = 0; mr < 2; ++mr) af[mr] =                 \
        *reinterpret_cast<const bf16x8*>(Lds + RD + abase + a_off[mr][1]);    \
    BARRIER();                                                                \
    __builtin_amdgcn_s_setprio(1);                                            \
    _Pragma("unroll") for (int mr = 0; mr < 2; ++mr) {                        \
      acc[mr][0] = __builtin_amdgcn_mfma_f32_16x16x32_bf16(af[mr], bf0,       \
                                                           acc[mr][0], 0, 0,  \
                                                           0);                \
      acc[mr][1] = __builtin_amdgcn_mfma_f32_16x16x32_bf16(af[mr], bf1,       \
                                                           acc[mr][1], 0, 0,  \
                                                           0);                \
      acc[mr][2] = __builtin_amdgcn_mfma_f32_16x16x32_bf16(af[mr], bf2,       \
                                                           acc[mr][2], 0, 0,  \
                                                           0);                \
    }                                                                         \
    __builtin_amdgcn_s_setprio(0);                                            \
    BARRIER();                                                                \
    /* P3: frags A ks1 mr2-3; MFMA acc[2..3]; drain staged loads */           \
    _Pragma("unroll") for (int mr = 0; mr < 2; ++mr) af[mr] =                 \
        *reinterpret_cast<const bf16x8*>(Lds + RD + abase +                   \
                                         a_off[mr + 2][1]);                   \
    BARRIER();                                                                \
    __builtin_amdgcn_s_setprio(1);                                            \
    _Pragma("unroll") for (int mr = 0; mr < 2; ++mr) {                        \
      acc[mr + 2][0] = __builtin_amdgcn_mfma_f32_16x16x32_bf16(               \
          af[mr], bf0, acc[mr + 2][0], 0, 0, 0);                              \
      acc[mr + 2][1] = __builtin_amdgcn_mfma_f32_16x16x32_bf16(               \
          af[mr], bf1, acc[mr + 2][1], 0, 0, 0);                              \
      acc[mr + 2][2] = __builtin_amdgcn_mfma_f32_16x16x32_bf16(               \
          af[mr], bf2, acc[mr + 2][2], 0, 0, 0);                              \
    }                                                                         \
    __builtin_amdgcn_s_setprio(0);                                            \
    asm volatile("s_waitcnt vmcnt(0)" ::: "memory");                          \
    BARRIER();                                                                \
  }

  for (int jj = 0; jj < 16; jj += 2) {
    TILE(jj, 0);
    TILE(jj + 1, 1);
  }
#undef TILE
#undef BARRIER

  // ---- epilogue ----
  const int wr = wm * 64;
  const int nqk = (n0 >= 2 * D_) ? 0
                  : ((2 * D_ - n0 < 192) ? (2 * D_ - n0) : 192);

  // V columns: per-lane kv-permuted b64 stores
#pragma unroll
  for (int nr = 0; nr < 3; ++nr) {
    const int c = wn * 48 + nr * 16 + l15;         // local col
    if (c >= nqk) {
      const int f = n0 + c - 2 * D_;               // v-feature 0..1023
      const float bias = bv[f];
      const int base0 = (m0 & 2047) + wr;          // multiple of 64
      short* vout = Vt + ((size_t)((m0 >> 11) * H_ + (f >> 6)) * DH_ +
                          (f & 63)) * S_;
#pragma unroll
      for (int mr = 0; mr < 4; ++mr) {             // rows mr*16+lg*4+r of 64
        bf16x4 pv;
#pragma unroll
        for (int r = 0; r < 4; ++r) pv[r] = f2bs(acc[mr][nr][r] + bias);
        const int s_new = base0 + ((mr >> 1) * 4 + lg) * 8 + (mr & 1) * 4;
        *reinterpret_cast<bf16x4*>(vout + s_new) = pv;
      }
    }
  }

  // Q/K columns: LDS-bounce for coalesced b128 stores (LDS dead after loop;
  // tile 128 rows x 400B stride = 51.2KB < 80KB).
  if (nqk > 0) {
#pragma unroll
    for (int nr = 0; nr < 3; ++nr) {
      const int c = wn * 48 + nr * 16 + l15;
      if (c < nqk) {                               // wave-uniform (x16 bounds)
        const int col = n0 + c;
        float bias, qs;
        if (col < D_) { bias = bq[col];      qs = 0.125f * L2E; }
        else          { bias = bk[col - D_]; qs = 1.f; }
#pragma unroll
        for (int mr = 0; mr < 4; ++mr)
#pragma unroll
          for (int r = 0; r < 4; ++r) {
            const int m = wr + mr * 16 + lg * 4 + r;
            *reinterpret_cast<short*>(Lds + m * 400 + c * 2) =
                f2bs((acc[mr][nr][r] + bias) * qs);
          }
      }
    }
    __builtin_amdgcn_s_barrier();
    const int ncch = nqk >> 3;                     // b128 chunk-cols per row
    const int total = 128 * ncch;
    for (int g = tid; g < total; g += 512) {
      const int m = g / ncch, cc = g - m * ncch;
      const f32x4 v =
          *reinterpret_cast<const f32x4*>(Lds + m * 400 + cc * 16);
      *reinterpret_cast<f32x4*>(
          &QKV[(size_t)(m0 + m) * ND3 + n0 + cc * 8]) = v;
    }
  }
}

// ----------------------------------------------------------- flash attention
// r17 attn verbatim (best measured ~33 us): q-split waves, static-offset
// softmax (SBIAS in a constant C register), raw v_exp_f32, v_perm_b32 pack,
// V read as b128 pairs (kv-permuted Vt), 2K+3V LDS slots (40KB), 4 blocks/CU,
// QK one tile ahead, raw barrier + vmcnt drain, XOR-swizzled staging, LPT.
__global__ __launch_bounds__(256, 4) void attn_kernel(
    const short* __restrict__ QKV, const short* __restrict__ Vtg,
    float* __restrict__ Out) {
  __shared__ short KV[5][4096];   // 40KB: K slots @0,8192; V @16384/24576/32768
  const int tid = threadIdx.x;
  const int lane = tid & 63, wid = tid >> 6;
  const int l15 = lane & 15, lg = lane >> 4;
  const int bh = blockIdx.x;
  const int qt = (S_ / 64 - 1) - (int)blockIdx.y;   // LPT: longest first
  const int b = bh >> 4, h = bh & 15;
  const int q0 = qt * 64;
  const short* Qg = QKV + (size_t)b * S_ * ND3 + h * DH_;
  const short* Kg = QKV + (size_t)b * S_ * ND3 + D_ + h * DH_;
  const short* Vg = Vtg + (size_t)bh * DH_ * S_;

  const int srow = tid >> 3;
  const int scol = ((tid & 7) ^ (srow & 7)) * 8;
  const char* kbase = (const char*)&KV[0][0];
  char* dst = (char*)kbase + (tid & 192) * 16;
  int ka[2];
#pragma unroll
  for (int ks = 0; ks < 2; ++ks)
    ka[ks] = l15 * 128 + ((((ks * 4 + lg)) ^ (l15 & 7)) << 4);
  const int qrow_g = q0 + wid * 16 + l15;

  bf16x8 qf[2];
#pragma unroll
  for (int ks = 0; ks < 2; ++ks)
    qf[ks] = *reinterpret_cast<const bf16x8*>(Qg + (size_t)qrow_g * ND3 +
                                              ks * 32 + lg * 8);

  const f32x4 cinit = (f32x4){SBIAS, SBIAS, SBIAS, SBIAS};  // constant C reg

  f32x4 o[4];
#pragma unroll
  for (int i = 0; i < 4; ++i) o[i] = (f32x4){0.f, 0.f, 0.f, 0.f};
  float lsum = 0.f;

  const short* kp = Kg + (size_t)srow * ND3 + scol;
  const short* vp = Vg + (size_t)srow * S_ + scol;

#define STAGE_AT(KOFF, VOFF)                                                  \
  {                                                                           \
    gl_lds16(kp, dst + (KOFF));                                               \
    gl_lds16(kp + 32 * ND3, dst + (KOFF) + 4096);                             \
    gl_lds16(vp, dst + (VOFF));                                               \
    gl_lds16(vp + 32 * S_, dst + (VOFF) + 4096);                              \
    kp += 64 * ND3;                                                           \
    vp += 64;                                                                 \
  }

  int kr = 8192, kw = 0;
  int vr = 16384, vw = 32768;          // VSUM = 73728

  STAGE_AT(0, 16384);
  if (qt >= 1) STAGE_AT(8192, 24576);
  asm volatile("s_waitcnt vmcnt(0)" ::: "memory");
  __builtin_amdgcn_s_barrier();
  __builtin_amdgcn_sched_barrier(0);

  f32x4 sA[4], sB[4];
#pragma unroll
  for (int nt = 0; nt < 4; ++nt)
    sA[nt] = __builtin_amdgcn_mfma_f32_16x16x32_bf16(
        *reinterpret_cast<const bf16x8*>(kbase + ka[0] + nt * 2048), qf[0],
        cinit, 0, 0, 0);
#pragma unroll
  for (int nt = 0; nt < 4; ++nt)
    sA[nt] = __builtin_amdgcn_mfma_f32_16x16x32_bf16(
        *reinterpret_cast<const bf16x8*>(kbase + ka[1] + nt * 2048), qf[1],
        sA[nt], 0, 0, 0);

#define STEP_BODY(T, SC, SN)                                                  \
  {                                                                           \
    const int T_ = (T);                                                       \
    if (T_ + 2 <= qt) STAGE_AT(kw, vw);                                       \
    if (T_ + 1 <= qt) {                                                       \
      _Pragma("unroll") for (int nt = 0; nt < 4; ++nt)                        \
          SN[nt] = __builtin_amdgcn_mfma_f32_16x16x32_bf16(                   \
              *reinterpret_cast<const bf16x8*>(kbase + kr + ka[0] +           \
                                               nt * 2048),                    \
              qf[0], cinit, 0, 0, 0);                                         \
      _Pragma("unroll") for (int nt = 0; nt < 4; ++nt)                        \
          SN[nt] = __builtin_amdgcn_mfma_f32_16x16x32_bf16(                   \
              *reinterpret_cast<const bf16x8*>(kbase + kr + ka[1] +           \
                                               nt * 2048),                    \
              qf[1], SN[nt], 0, 0, 0);                                        \
    }                                                                         \
    if (T_ == qt) { /* causal mask on diagonal tile */                        \
      const int kv0 = T_ * 64;                                                \
      _Pragma("unroll") for (int nt = 0; nt < 4; ++nt)                        \
        _Pragma("unroll") for (int r = 0; r < 4; ++r)                         \
          if (kv0 + nt * 16 + lg * 4 + r > qrow_g) SC[nt][r] = MASKVAL;       \
    }                                                                         \
    float rowsum = 0.f;                                                       \
    bf16x4 pk[4];                                                             \
    _Pragma("unroll") for (int nt = 0; nt < 4; ++nt) {                        \
      const float p0 = EXP2(SC[nt][0]);                                       \
      const float p1 = EXP2(SC[nt][1]);                                       \
      const float p2 = EXP2(SC[nt][2]);                                       \
      const float p3 = EXP2(SC[nt][3]);                                       \
      rowsum += (p0 + p1) + (p2 + p3);                                        \
      union { uint32_t u[2]; bf16x4 v; } pu;                                  \
      pu.u[0] = __builtin_amdgcn_perm(__float_as_uint(p1),                    \
                                      __float_as_uint(p0), 0x07060302u);      \
      pu.u[1] = __builtin_amdgcn_perm(__float_as_uint(p3),                    \
                                      __float_as_uint(p2), 0x07060302u);      \
      pk[nt] = pu.v;                                                          \
    }                                                                         \
    lsum += rowsum;                                                           \
    _Pragma("unroll") for (int p = 0; p < 2; ++p)                             \
      _Pragma("unroll") for (int ntd = 0; ntd < 4; ++ntd) {                   \
        const bf16x8 vf8 = *reinterpret_cast<const bf16x8*>(                  \
            kbase + vr + ka[p] + ntd * 2048);                                 \
        const bf16x4 vlo = __builtin_shufflevector(vf8, vf8, 0, 1, 2, 3);     \
        const bf16x4 vhi = __builtin_shufflevector(vf8, vf8, 4, 5, 6, 7);     \
        o[ntd] = __builtin_amdgcn_mfma_f32_16x16x16bf16_1k(vlo, pk[2 * p],    \
                                                           o[ntd], 0, 0, 0);  \
        o[ntd] = __builtin_amdgcn_mfma_f32_16x16x16bf16_1k(                   \
            vhi, pk[2 * p + 1], o[ntd], 0, 0, 0);                             \
      }                                                                       \
    if (T_ < qt) {                                                            \
      asm volatile("s_waitcnt vmcnt(0)" ::: "memory");                        \
      __builtin_amdgcn_s_barrier();                                           \
      __builtin_amdgcn_sched_barrier(0);                                      \
    }                                                                         \
    kr ^= 8192; kw ^= 8192;                                                   \
    { const int tv = vr; vr = 73728 - vr - vw; vw = tv; }                     \
  }

  for (int t = 0; t <= qt; t += 2) {
    STEP_BODY(t, sA, sB);
    if (t + 1 <= qt) STEP_BODY(t + 1, sB, sA);
  }
#undef STEP_BODY
#undef STAGE_AT

  float ls = lsum;
  ls += __shfl_xor(ls, 16);
  ls += __shfl_xor(ls, 32);
  const float inv = 1.f / ls;
#pragma unroll
  for (int nt = 0; nt < 4; ++nt) {
    f32x4 v = {o[nt][0] * inv, o[nt][1] * inv, o[nt][2] * inv, o[nt][3] * inv};
    *reinterpret_cast<f32x4*>(
        &Out[((size_t)b * S_ + qrow_g) * D_ + h * DH_ + nt * 16 + lg * 4]) = v;
  }
}

// ---------------------------------------------------------------- launcher
extern "C" void kernel_launch(void* const* d_in, const int* in_sizes, int n_in,
                              void* d_out, int out_size, void* d_ws,
                              size_t ws_size, hipStream_t stream) {
  const float* x  = (const float*)d_in[0];
  const float* Wq = (const float*)d_in[1];
  const float* bq = (const float*)d_in[2];
  const float* Wk = (const float*)d_in[3];
  const float* bk = (const float*)d_in[4];
  const float* Wv = (const float*)d_in[5];
  const float* bv = (const float*)d_in[6];
  float* out = (float*)d_out;

  char* ws = (char*)d_ws;
  short* xb  = (short*)(ws);             //  8 MB: [4096][1024] bf16
  short* Wt  = (short*)(ws + 8388608);   //  6 MB: [3072][1024] bf16
  short* qkv = (short*)(ws + 14680064);  // 24 MB: [4096][3072] bf16 (V unused)
  short* Vt  = (short*)(ws + 39845888);  //  8 MB: [32][64][2048] bf16 (kv-permuted)

  prep_kernel<<<dim3(4096 + 3072), dim3(256), 0, stream>>>(x, Wq, Wk, Wv, xb,
                                                           Wt);
  qkv_gemm_kernel<<<dim3(512), dim3(512), 0, stream>>>(xb, Wt, bq, bk, bv,
                                                       qkv, Vt);
  attn_kernel<<<dim3(B_ * H_, S_ / 64), dim3(256), 0, stream>>>(qkv, Vt, out);
}